// Round 16
// baseline (321.133 us; speedup 1.0000x reference)
//
#include <hip/hip_runtime.h>
#include <math.h>

#define B_ 4
#define N_ 2048
#define D_ 512
#define M_ 1024
#define H_ 8
#define DH_ 64
#define I_ 512
#define FF_ 1024

typedef unsigned short u16;
typedef __attribute__((ext_vector_type(8))) short bf16x8;
typedef __attribute__((ext_vector_type(4))) float f32x4;

__device__ inline u16 f2b(float f) {           // fp32 -> bf16 RNE
  union { float f; unsigned int u; } v; v.f = f;
  unsigned int u = v.u;
  u += 0x7fffu + ((u >> 16) & 1u);
  return (u16)(u >> 16);
}
__device__ inline float b2f(u16 h) {
  union { unsigned int u; float f; } v; v.u = ((unsigned int)h) << 16;
  return v.f;
}
__device__ inline float ex2(float x) { return __builtin_amdgcn_exp2f(x); }
// packed fp32x2 -> bf16x2 (RNE), one instruction; lo -> [15:0], hi -> [31:16]
__device__ inline unsigned int cvtpk(float lo, float hi) {
  unsigned int r;
  asm("v_cvt_pk_bf16_f32 %0, %1, %2" : "=v"(r) : "v"(lo), "v"(hi));
  return r;
}

__device__ inline float gelu_f(float x) {
  float x3 = x * x * x;
  return 0.5f * x * (1.f + tanhf(0.7978845608028654f * (x + 0.044715f * x3)));
}

__device__ inline bool better(float d1, int i1, float d2, int i2) {
  return d1 < d2 || (d1 == d2 && i1 < i2);
}
__device__ inline void cswap(float& da, int& ia, float& db, int& ib) {
  if (better(db, ib, da, ia)) {
    float td = da; da = db; db = td;
    int ti = ia; ia = ib; ib = ti;
  }
}
__device__ inline void kmin(float& da, int& ia, float db, int ib) {
  if (better(db, ib, da, ia)) { da = db; ia = ib; }
}

// ---------------- zero accumulators ----------------
__global__ void zero_init_kernel(float* counts) {
  counts[threadIdx.x] = 0.f;
}

// ---------------- mask dtype detection / normalize ----------------
__global__ void mask_detect_kernel(const unsigned char* __restrict__ mb, int* flag) {
  __shared__ int any;
  if (threadIdx.x == 0) any = 0;
  __syncthreads();
  int acc = 0;
  for (int i = threadIdx.x; i < 8192; i += 256)
    if (i & 3) acc |= mb[i];
  if (acc) atomicOr(&any, 1);
  __syncthreads();
  if (threadIdx.x == 0) *flag = any;
}

__global__ void mask_norm_kernel(const void* __restrict__ mraw,
                                 const int* __restrict__ flag,
                                 int* __restrict__ mnorm) {
  int i = blockIdx.x * 256 + threadIdx.x;
  int v;
  if (*flag) v = ((const unsigned char*)mraw)[i];
  else       v = ((const int*)mraw)[i];
  mnorm[i] = (v != 0) ? 1 : 0;
}

// ---------------- codebook row sum-of-squares (fp64 + fp32 copy) ----------------
__global__ __launch_bounds__(128) void code_sq_kernel(const float* __restrict__ cb,
                                                      double* __restrict__ csq,
                                                      float* __restrict__ csqf) {
  int row = blockIdx.x, tid = threadIdx.x;
  const float4* r4 = (const float4*)(cb + (size_t)row * D_);
  float4 v = r4[tid];
  double s = (double)v.x * v.x + (double)v.y * v.y + (double)v.z * v.z + (double)v.w * v.w;
  for (int off = 32; off; off >>= 1) s += __shfl_down(s, off);
  __shared__ double red[2];
  if ((tid & 63) == 0) red[tid >> 6] = s;
  __syncthreads();
  if (tid == 0) { csq[row] = red[0] + red[1]; csqf[row] = (float)(red[0] + red[1]); }
}

// ---------------- plain fp32 -> bf16 conversion (8 elems/thread) ----------------
__global__ __launch_bounds__(256) void conv_bf16_kernel(const float* __restrict__ src,
                                                        u16* __restrict__ dst) {
  int i = (blockIdx.x * 256 + threadIdx.x) * 8;
  float4 a = *(const float4*)(src + i);
  float4 b = *(const float4*)(src + i + 4);
  uint4 o;
  o.x = cvtpk(a.x, a.y);
  o.y = cvtpk(a.z, a.w);
  o.z = cvtpk(b.x, b.y);
  o.w = cvtpk(b.z, b.w);
  *(uint4*)(dst + i) = o;
}

// ---------------- VQ: reduce per-colblock top-4 partials -> top-4 cand ----------------
__global__ __launch_bounds__(256) void vq_top4_reduce_kernel(
    const float4* __restrict__ cand_part, int4* __restrict__ cand4)
{
  int t = blockIdx.x * 256 + threadIdx.x;
  float d0 = 1e30f, d1 = 1e30f, d2 = 1e30f, d3 = 1e30f;
  int x0 = 1 << 20, x1 = 1 << 21, x2 = 1 << 22, x3 = 1 << 23;
#pragma unroll
  for (int cb = 0; cb < 16; cb++) {
    float4 a = cand_part[(size_t)t * 32 + cb * 2];
    float4 b = cand_part[(size_t)t * 32 + cb * 2 + 1];
    float e0 = a.x, e1 = a.y, e2 = b.x, e3 = b.y;
    int y0 = __float_as_int(a.z), y1 = __float_as_int(a.w);
    int y2 = __float_as_int(b.z), y3 = __float_as_int(b.w);
    kmin(d0, x0, e3, y3); kmin(d1, x1, e2, y2);
    kmin(d2, x2, e1, y1); kmin(d3, x3, e0, y0);
    cswap(d0, x0, d2, x2); cswap(d1, x1, d3, x3);
    cswap(d0, x0, d1, x1); cswap(d2, x2, d3, x3);
  }
  cand4[t] = make_int4(x0, x1, x2, x3);
}

// ---------------- VQ: exact fp64 refine over 4 candidates + commit + histogram ------
__global__ __launch_bounds__(256) void vq_refine4_kernel(
    const float* __restrict__ flat, const float* __restrict__ cb,
    const double* __restrict__ csq, const int4* __restrict__ cand4,
    int* __restrict__ out_idx, double* __restrict__ commit_partial,
    float* __restrict__ counts)
{
  int wave = threadIdx.x >> 6, lane = threadIdx.x & 63;
  int t = blockIdx.x * 4 + wave;
  int4 c = cand4[t];
  const float* x = flat + ((size_t)t << 9);
  const float* p0 = cb + ((size_t)c.x << 9);
  const float* p1 = cb + ((size_t)c.y << 9);
  const float* p2 = cb + ((size_t)c.z << 9);
  const float* p3 = cb + ((size_t)c.w << 9);
  double s0 = 0.0, s1 = 0.0, s2 = 0.0, s3 = 0.0, sx = 0.0;
#pragma unroll
  for (int i = 0; i < 8; i++) {
    int d = lane + i * 64;
    double xv = x[d];
    s0 += xv * (double)p0[d];
    s1 += xv * (double)p1[d];
    s2 += xv * (double)p2[d];
    s3 += xv * (double)p3[d];
    sx += xv * xv;
  }
  for (int off = 32; off; off >>= 1) {
    s0 += __shfl_down(s0, off);
    s1 += __shfl_down(s1, off);
    s2 += __shfl_down(s2, off);
    s3 += __shfl_down(s3, off);
    sx += __shfl_down(sx, off);
  }
  if (lane == 0) {
    double dd0 = csq[c.x] - 2.0 * s0;
    double dd1 = csq[c.y] - 2.0 * s1;
    double dd2 = csq[c.z] - 2.0 * s2;
    double dd3 = csq[c.w] - 2.0 * s3;
    int bi = c.x; double bd = dd0;
    if (dd1 < bd || (dd1 == bd && c.y < bi)) { bd = dd1; bi = c.y; }
    if (dd2 < bd || (dd2 == bd && c.z < bi)) { bd = dd2; bi = c.z; }
    if (dd3 < bd || (dd3 == bd && c.w < bi)) { bd = dd3; bi = c.w; }
    out_idx[t] = bi;
    commit_partial[t] = sx + bd;
    atomicAdd(counts + bi, 1.0f);
  }
}

// ---------------- LayerNorm (fp32 in -> bf16 out) ----------------
__global__ __launch_bounds__(256) void ln_rows_kernel(
    const float* __restrict__ x, const float* __restrict__ g,
    const float* __restrict__ b, u16* __restrict__ y)
{
  int row = blockIdx.x, tid = threadIdx.x;
  const float* xr = x + (size_t)row * D_;
  float v0 = xr[tid], v1 = xr[tid + 256];
  float s = v0 + v1;
  for (int off = 32; off; off >>= 1) s += __shfl_down(s, off);
  __shared__ float red[4];
  __shared__ float bcast[2];
  if ((tid & 63) == 0) red[tid >> 6] = s;
  __syncthreads();
  if (tid == 0) bcast[0] = (red[0] + red[1] + red[2] + red[3]) * (1.f / 512.f);
  __syncthreads();
  float mu = bcast[0];
  float d0 = v0 - mu, d1 = v1 - mu;
  float q = d0 * d0 + d1 * d1;
  for (int off = 32; off; off >>= 1) q += __shfl_down(q, off);
  if ((tid & 63) == 0) red[tid >> 6] = q;
  __syncthreads();
  if (tid == 0) bcast[1] = rsqrtf((red[0] + red[1] + red[2] + red[3]) * (1.f / 512.f) + 1e-5f);
  __syncthreads();
  float rs = bcast[1];
  u16* yr = y + (size_t)row * D_;
  yr[tid]       = f2b(d0 * rs * g[tid] + b[tid]);
  yr[tid + 256] = f2b(d1 * rs * g[tid + 256] + b[tid + 256]);
}

// ---------------- fused weight conversion ----------------
struct WJobs {
  const float* src[7];
  u16* dst[7];
  int K[7], N[7], b0[8];
};

__global__ __launch_bounds__(256) void wconv_all_kernel(WJobs jobs) {
  __shared__ float tile[32][33];
  int bid = blockIdx.x;
  int j = 0;
#pragma unroll
  for (int i = 1; i < 7; i++) if (bid >= jobs.b0[i]) j = i;
  int tb = bid - jobs.b0[j];
  int K = jobs.K[j], Nn = jobs.N[j];
  int tiles_x = Nn >> 5;
  int n0 = (tb % tiles_x) << 5, k0 = (tb / tiles_x) << 5;
  const float* W = jobs.src[j];
  u16* WT = jobs.dst[j];
  int t = threadIdx.x;
  int ty = t >> 5, tx = t & 31;
#pragma unroll
  for (int i = 0; i < 4; i++)
    tile[ty + 8 * i][tx] = W[(size_t)(k0 + ty + 8 * i) * Nn + n0 + tx];
  __syncthreads();
#pragma unroll
  for (int i = 0; i < 4; i++)
    WT[(size_t)(n0 + ty + 8 * i) * K + k0 + tx] = f2b(tile[tx][ty + 8 * i]);
}

// ---------------- bf16 MFMA GEMM, templated tile width ----------------
template <int BN>
__global__ __launch_bounds__(256, 4) void gemm_bf16_kernel(
    const u16* __restrict__ A, const u16* __restrict__ BT,
    const float* __restrict__ bias, const float* __restrict__ resid,
    float* __restrict__ Cf, u16* __restrict__ Cb,
    const float* __restrict__ csqf, float4* __restrict__ cand_part,
    int M, int N, int K, int act)
{
  constexpr int MF = (BN == 128) ? 4 : 2;
  constexpr int ROWS_W = (BN == 128) ? 64 : 32;
  __shared__ __attribute__((aligned(16))) u16 As[2][128 * 40];
  __shared__ __attribute__((aligned(16))) u16 Bs[2][BN * 40];
  int tid = threadIdx.x;
  int lane = tid & 63, wave = tid >> 6;
  int wr = (BN == 128) ? (wave >> 1) : wave;
  int wc = (BN == 128) ? (wave & 1) : 0;
  int nwgx = gridDim.x;
  int nwg = nwgx * gridDim.y;
  int flat = blockIdx.y * nwgx + blockIdx.x;
  if ((nwg & 7) == 0) flat = (flat & 7) * (nwg >> 3) + (flat >> 3);
  int row0 = (flat / nwgx) << 7, col0 = (flat % nwgx) * BN;
  int l15 = lane & 15, l4 = lane >> 4;
  int sr = tid >> 2, skc = tid & 3;
  int soff = sr * 40 + skc * 8;
  const u16* pA0 = A + (size_t)(row0 + sr) * K + skc * 8;
  const u16* pA1 = A + (size_t)(row0 + 64 + sr) * K + skc * 8;
  const u16* pB0 = BT + (size_t)(col0 + sr) * K + skc * 8;
  const u16* pB1 = (BN == 128) ? (BT + (size_t)(col0 + 64 + sr) * K + skc * 8) : nullptr;
  f32x4 acc[MF][4] = {};
  int KT = K >> 5;
  bf16x8 ra0 = *(const bf16x8*)pA0;
  bf16x8 ra1 = *(const bf16x8*)pA1;
  bf16x8 rb0 = *(const bf16x8*)pB0;
  bf16x8 rb1;
  if constexpr (BN == 128) rb1 = *(const bf16x8*)pB1;
  *(bf16x8*)&As[0][soff] = ra0;
  *(bf16x8*)&As[0][64 * 40 + soff] = ra1;
  *(bf16x8*)&Bs[0][soff] = rb0;
  if constexpr (BN == 128) *(bf16x8*)&Bs[0][64 * 40 + soff] = rb1;
  if (KT > 1) {
    ra0 = *(const bf16x8*)(pA0 + 32);
    ra1 = *(const bf16x8*)(pA1 + 32);
    rb0 = *(const bf16x8*)(pB0 + 32);
    if constexpr (BN == 128) rb1 = *(const bf16x8*)(pB1 + 32);
  }
  for (int kt = 0; kt < KT; kt++) {
    int cur = kt & 1;
    __syncthreads();
    if (kt + 1 < KT) {
      *(bf16x8*)&As[cur ^ 1][soff] = ra0;
      *(bf16x8*)&As[cur ^ 1][64 * 40 + soff] = ra1;
      *(bf16x8*)&Bs[cur ^ 1][soff] = rb0;
      if constexpr (BN == 128) *(bf16x8*)&Bs[cur ^ 1][64 * 40 + soff] = rb1;
    }
    if (kt + 2 < KT) {
      int ko = (kt + 2) << 5;
      ra0 = *(const bf16x8*)(pA0 + ko);
      ra1 = *(const bf16x8*)(pA1 + ko);
      rb0 = *(const bf16x8*)(pB0 + ko);
      if constexpr (BN == 128) rb1 = *(const bf16x8*)(pB1 + ko);
    }
    bf16x8 af[MF], bfr[4];
#pragma unroll
    for (int m = 0; m < MF; m++)
      af[m] = *(const bf16x8*)&As[cur][(wr * ROWS_W + m * 16 + l15) * 40 + l4 * 8];
#pragma unroll
    for (int n = 0; n < 4; n++)
      bfr[n] = *(const bf16x8*)&Bs[cur][(wc * 64 + n * 16 + l15) * 40 + l4 * 8];
#pragma unroll
    for (int m = 0; m < MF; m++)
#pragma unroll
      for (int n = 0; n < 4; n++)
        acc[m][n] = __builtin_amdgcn_mfma_f32_16x16x32_bf16(af[m], bfr[n], acc[m][n], 0, 0, 0);
  }
  if constexpr (BN == 128) {
    if (act == 2) {
      float csq_l[4];
#pragma unroll
      for (int n = 0; n < 4; n++) csq_l[n] = csqf[col0 + wc * 64 + n * 16 + l15];
      int cbase = col0 + wc * 64 + l15;
      int slot = ((col0 >> 7) << 1) + wc;
#pragma unroll
      for (int m = 0; m < 4; m++) {
#pragma unroll
        for (int r = 0; r < 4; r++) {
          float d0 = csq_l[0] - 2.f * acc[m][0][r];
          float d1 = csq_l[1] - 2.f * acc[m][1][r];
          float d2 = csq_l[2] - 2.f * acc[m][2][r];
          float d3 = csq_l[3] - 2.f * acc[m][3][r];
          int x0 = cbase, x1 = cbase + 16, x2 = cbase + 32, x3 = cbase + 48;
          cswap(d0, x0, d1, x1); cswap(d2, x2, d3, x3);
          cswap(d0, x0, d2, x2); cswap(d1, x1, d3, x3);
          cswap(d1, x1, d2, x2);
          for (int off = 1; off < 16; off <<= 1) {
            float e0 = __shfl_xor(d0, off), e1 = __shfl_xor(d1, off);
            float e2 = __shfl_xor(d2, off), e3 = __shfl_xor(d3, off);
            int y0 = __shfl_xor(x0, off), y1 = __shfl_xor(x1, off);
            int y2 = __shfl_xor(x2, off), y3 = __shfl_xor(x3, off);
            kmin(d0, x0, e3, y3); kmin(d1, x1, e2, y2);
            kmin(d2, x2, e1, y1); kmin(d3, x3, e0, y0);
            cswap(d0, x0, d2, x2); cswap(d1, x1, d3, x3);
            cswap(d0, x0, d1, x1); cswap(d2, x2, d3, x3);
          }
          if (l15 == 0) {
            int row = row0 + wr * 64 + m * 16 + l4 * 4 + r;
            float4 v1, v2;
            v1.x = d0; v1.y = d1;
            v1.z = __int_as_float(x0); v1.w = __int_as_float(x1);
            v2.x = d2; v2.y = d3;
            v2.z = __int_as_float(x2); v2.w = __int_as_float(x3);
            cand_part[(size_t)row * 32 + slot * 2]     = v1;
            cand_part[(size_t)row * 32 + slot * 2 + 1] = v2;
          }
        }
      }
      return;
    }
  }
#pragma unroll
  for (int m = 0; m < MF; m++) {
#pragma unroll
    for (int n = 0; n < 4; n++) {
      int col = col0 + wc * 64 + n * 16 + l15;
      float bv = bias ? bias[col] : 0.f;
#pragma unroll
      for (int r = 0; r < 4; r++) {
        int row = row0 + wr * ROWS_W + m * 16 + l4 * 4 + r;
        float v = acc[m][n][r] + bv;
        if (act == 1) v = gelu_f(v);
        if (resid) v += resid[(size_t)row * N + col];
        if (Cf) Cf[(size_t)row * N + col] = v;
        if (Cb) Cb[(size_t)row * N + col] = f2b(v);
      }
    }
  }
}

// ---------------- V transpose: src rows -> Vt [b*8+h][64][n_rows] ----------------
__global__ __launch_bounds__(256) void vt_kernel(
    const u16* __restrict__ src, size_t b_stride, int row_stride, int col0,
    int n_rows, u16* __restrict__ dst)
{
  __shared__ __attribute__((aligned(16))) u16 tile[32][72];
  int t = threadIdx.x;
  int bh = blockIdx.y;
  int b = bh >> 3, h = bh & 7;
  int n0 = blockIdx.x * 32;
  int n = t >> 3, dc = t & 7;
  *(bf16x8*)&tile[n][dc * 8] =
      *(const bf16x8*)(src + (size_t)b * b_stride + (size_t)(n0 + n) * row_stride + col0 + h * 64 + dc * 8);
  __syncthreads();
  int d = t >> 2, ns = t & 3;
  bf16x8 o;
#pragma unroll
  for (int i = 0; i < 8; i++) o[i] = (short)tile[ns * 8 + i][d];
  *(bf16x8*)(dst + ((size_t)bh * 64 + d) * n_rows + n0 + ns * 8) = o;
}

// ---------------- MFMA flash attention: 32 q/wave, split-K 4, cvt_pk softmax ----
__global__ __launch_bounds__(256, 4) void attn_mfma_kernel(
    const u16* __restrict__ Q, size_t q_bs, int q_stride,
    const u16* __restrict__ Kp, size_t k_bs, int k_stride, int k_extra,
    const u16* __restrict__ Vt, const int* __restrict__ mask,
    float scale, u16* __restrict__ Opart, float* __restrict__ MLpart,
    int n_keys)
{
  __shared__ __attribute__((aligned(16))) u16 Ks[8 * 64 * 8];
  __shared__ __attribute__((aligned(16))) u16 Vs[8 * 64 * 8];
  __shared__ __attribute__((aligned(16))) u16 Ps[4][8 * 32 * 8];
  __shared__ float mbias[64];
  int tid = threadIdx.x, lane = tid & 63, wave = tid >> 6;
  int flat = blockIdx.x + (blockIdx.y << 3) + (blockIdx.z << 6);
  int swz = ((flat & 7) << 7) + (flat >> 3);
  int qb = swz & 7, h = (swz >> 3) & 7, z = swz >> 6;
  int b = z & 3, split = z >> 2;
  int q0 = qb * 128 + wave * 32;
  int l15 = lane & 15, l4 = lane >> 4;
  int nq = n_keys >> 2;
  int nstart = split * nq, nend = nstart + nq;

  const u16* qrow = Q + (size_t)b * q_bs + (size_t)(q0 + l15) * q_stride + h * 64 + l4 * 8;
  bf16x8 qfA0 = *(const bf16x8*)qrow;
  bf16x8 qfA1 = *(const bf16x8*)(qrow + 32);
  const u16* qrowB = qrow + 16 * q_stride;
  bf16x8 qfB0 = *(const bf16x8*)qrowB;
  bf16x8 qfB1 = *(const bf16x8*)(qrowB + 32);
  f32x4 oA[4] = {}, oB[4] = {};
  float mA = -3.0e38f, lA = 0.f, mB = -3.0e38f, lB = 0.f;
  int srow = tid >> 2, schunk = tid & 3;
  const u16* kbase = Kp + (size_t)b * k_bs + k_extra + h * 64;
  const u16* vtbase = Vt + (size_t)(b * 8 + h) * 64 * n_keys;

  bf16x8 pk0, pk1, pv0, pv1;
  int pmv = 1;
  {
    const u16* krow = kbase + (size_t)(nstart + srow) * k_stride;
    pk0 = *(const bf16x8*)(krow + schunk * 8);
    pk1 = *(const bf16x8*)(krow + (schunk + 4) * 8);
    const u16* vrow = vtbase + (size_t)srow * n_keys + nstart;
    pv0 = *(const bf16x8*)(vrow + schunk * 8);
    pv1 = *(const bf16x8*)(vrow + (schunk + 4) * 8);
    if (mask && tid < 64) pmv = mask[(size_t)b * n_keys + nstart + tid];
  }

  for (int n0 = nstart; n0 < nend; n0 += 64) {
    __syncthreads();
    *(bf16x8*)&Ks[(schunk * 64 + srow) * 8]       = pk0;
    *(bf16x8*)&Ks[((schunk + 4) * 64 + srow) * 8] = pk1;
    *(bf16x8*)&Vs[(schunk * 64 + srow) * 8]       = pv0;
    *(bf16x8*)&Vs[((schunk + 4) * 64 + srow) * 8] = pv1;
    if (tid < 64) mbias[tid] = (mask && !pmv) ? -3.0e38f : 0.f;
    __syncthreads();
    if (n0 + 64 < nend) {
      const u16* krow = kbase + (size_t)(n0 + 64 + srow) * k_stride;
      pk0 = *(const bf16x8*)(krow + schunk * 8);
      pk1 = *(const bf16x8*)(krow + (schunk + 4) * 8);
      const u16* vrow = vtbase + (size_t)srow * n_keys + n0 + 64;
      pv0 = *(const bf16x8*)(vrow + schunk * 8);
      pv1 = *(const bf16x8*)(vrow + (schunk + 4) * 8);
      if (mask && tid < 64) pmv = mask[(size_t)b * n_keys + n0 + 64 + tid];
    }
    // swapped QK^T for both query halves; K-frags read once, shared.
    f32x4 sacA[4], sacB[4];
#pragma unroll
    for (int kb = 0; kb < 4; kb++) {
      bf16x8 kf0 = *(const bf16x8*)&Ks[(l4 * 64 + kb * 16 + l15) * 8];
      bf16x8 kf1 = *(const bf16x8*)&Ks[((l4 + 4) * 64 + kb * 16 + l15) * 8];
      f32x4 za = {}, zb = {};
      za = __builtin_amdgcn_mfma_f32_16x16x32_bf16(kf0, qfA0, za, 0, 0, 0);
      sacA[kb] = __builtin_amdgcn_mfma_f32_16x16x32_bf16(kf1, qfA1, za, 0, 0, 0);
      zb = __builtin_amdgcn_mfma_f32_16x16x32_bf16(kf0, qfB0, zb, 0, 0, 0);
      sacB[kb] = __builtin_amdgcn_mfma_f32_16x16x32_bf16(kf1, qfB1, zb, 0, 0, 0);
    }
    // ---- softmax half A (query = l15) ----
    {
      float pmax = -3.0e38f;
#pragma unroll
      for (int kb = 0; kb < 4; kb++) {
        float4 bs = *(const float4*)&mbias[kb * 16 + l4 * 4];
        sacA[kb][0] = fmaf(sacA[kb][0], scale, bs.x);
        sacA[kb][1] = fmaf(sacA[kb][1], scale, bs.y);
        sacA[kb][2] = fmaf(sacA[kb][2], scale, bs.z);
        sacA[kb][3] = fmaf(sacA[kb][3], scale, bs.w);
#pragma unroll
        for (int r = 0; r < 4; r++) pmax = fmaxf(pmax, sacA[kb][r]);
      }
      pmax = fmaxf(pmax, __shfl_xor(pmax, 16));
      pmax = fmaxf(pmax, __shfl_xor(pmax, 32));
      if (!__all(pmax - mA <= 11.5f)) {
        float mnew = fmaxf(mA, pmax);
        float al = ex2(mA - mnew);
        lA *= al;
        mA = mnew;
        float alr[4];
#pragma unroll
        for (int r = 0; r < 4; r++) alr[r] = __shfl(al, l4 * 4 + r, 64);
#pragma unroll
        for (int nb = 0; nb < 4; nb++)
#pragma unroll
          for (int r = 0; r < 4; r++) oA[nb][r] *= alr[r];
      }
      float psum = 0.f;
#pragma unroll
      for (int kb = 0; kb < 4; kb++) {
        float p0 = ex2(sacA[kb][0] - mA);
        float p1 = ex2(sacA[kb][1] - mA);
        float p2 = ex2(sacA[kb][2] - mA);
        float p3 = ex2(sacA[kb][3] - mA);
        psum += (p0 + p1) + (p2 + p3);
        uint2 w;
        w.x = cvtpk(p0, p1);
        w.y = cvtpk(p2, p3);
        *(uint2*)&Ps[wave][((kb * 2 + (l4 >> 1)) * 32 + l15) * 8 + (l4 & 1) * 4] = w;
      }
      psum += __shfl_xor(psum, 16);
      psum += __shfl_xor(psum, 32);
      lA += psum;
    }
    // ---- softmax half B (query = 16 + l15) ----
    {
      float pmax = -3.0e38f;
#pragma unroll
      for (int kb = 0; kb < 4; kb++) {
        float4 bs = *(const float4*)&mbias[kb * 16 + l4 * 4];
        sacB[kb][0] = fmaf(sacB[kb][0], scale, bs.x);
        sacB[kb][1] = fmaf(sacB[kb][1], scale, bs.y);
        sacB[kb][2] = fmaf(sacB[kb][2], scale, bs.z);
        sacB[kb][3] = fmaf(sacB[kb][3], scale, bs.w);
#pragma unroll
        for (int r = 0; r < 4; r++) pmax = fmaxf(pmax, sacB[kb][r]);
      }
      pmax = fmaxf(pmax, __shfl_xor(pmax, 16));
      pmax = fmaxf(pmax, __shfl_xor(pmax, 32));
      if (!__all(pmax - mB <= 11.5f)) {
        float mnew = fmaxf(mB, pmax);
        float al = ex2(mB - mnew);
        lB *= al;
        mB = mnew;
        float alr[4];
#pragma unroll
        for (int r = 0; r < 4; r++) alr[r] = __shfl(al, l4 * 4 + r, 64);
#pragma unroll
        for (int nb = 0; nb < 4; nb++)
#pragma unroll
          for (int r = 0; r < 4; r++) oB[nb][r] *= alr[r];
      }
      float psum = 0.f;
#pragma unroll
      for (int kb = 0; kb < 4; kb++) {
        float p0 = ex2(sacB[kb][0] - mB);
        float p1 = ex2(sacB[kb][1] - mB);
        float p2 = ex2(sacB[kb][2] - mB);
        float p3 = ex2(sacB[kb][3] - mB);
        psum += (p0 + p1) + (p2 + p3);
        uint2 w;
        w.x = cvtpk(p0, p1);
        w.y = cvtpk(p2, p3);
        *(uint2*)&Ps[wave][((kb * 2 + (l4 >> 1)) * 32 + 16 + l15) * 8 + (l4 & 1) * 4] = w;
      }
      psum += __shfl_xor(psum, 16);
      psum += __shfl_xor(psum, 32);
      lB += psum;
    }
    // ---- PV: V-frags read once, shared by both halves ----
#pragma unroll
    for (int c = 0; c < 2; c++) {
      bf16x8 pfA = *(const bf16x8*)&Ps[wave][((c * 4 + l4) * 32 + l15) * 8];
      bf16x8 pfB = *(const bf16x8*)&Ps[wave][((c * 4 + l4) * 32 + 16 + l15) * 8];
#pragma unroll
      for (int nb = 0; nb < 4; nb++) {
        bf16x8 vf = *(const bf16x8*)&Vs[((c * 4 + l4) * 64 + nb * 16 + l15) * 8];
        oA[nb] = __builtin_amdgcn_mfma_f32_16x16x32_bf16(pfA, vf, oA[nb], 0, 0, 0);
        oB[nb] = __builtin_amdgcn_mfma_f32_16x16x32_bf16(pfB, vf, oB[nb], 0, 0, 0);
      }
    }
  }
  int pr_base = ((split * 4 + b) * 8 + h) * 1024;
#pragma unroll
  for (int nb = 0; nb < 4; nb++)
#pragma unroll
    for (int r = 0; r < 4; r++) {
      Opart[(size_t)(pr_base + q0 + l4 * 4 + r) * 64 + nb * 16 + l15] = f2b(oA[nb][r]);
      Opart[(size_t)(pr_base + q0 + 16 + l4 * 4 + r) * 64 + nb * 16 + l15] = f2b(oB[nb][r]);
    }
  if (lane < 16) {
    int pr = pr_base + q0 + lane;
    MLpart[2 * pr]     = mA;
    MLpart[2 * pr + 1] = lA;
  } else if (lane < 32) {
    int pr = pr_base + q0 + 16 + l15;
    MLpart[2 * pr]     = mB;
    MLpart[2 * pr + 1] = lB;
  }
}

// ---------------- combine the 4 split-K partials (base-2 weights) ----------------
__global__ __launch_bounds__(256) void attn_combine_kernel(
    const u16* __restrict__ Opart, const float* __restrict__ MLpart,
    u16* __restrict__ O, size_t o_bs)
{
  int idx = blockIdx.x * 256 + threadIdx.x;
  int d = idx & 63, gq = idx >> 6;
  int row = gq & 1023, bh = gq >> 10;
  int h = bh & 7, b = bh >> 3;
  float m[4], l[4];
  int pr[4];
#pragma unroll
  for (int s = 0; s < 4; s++) {
    pr[s] = ((s * 4 + b) * 8 + h) * 1024 + row;
    m[s] = MLpart[2 * pr[s]];
    l[s] = MLpart[2 * pr[s] + 1];
  }
  float mmax = fmaxf(fmaxf(m[0], m[1]), fmaxf(m[2], m[3]));
  float lsum = 0.f, osum = 0.f;
#pragma unroll
  for (int s = 0; s < 4; s++) {
    float w = ex2(m[s] - mmax);
    lsum += l[s] * w;
    osum += b2f(Opart[(size_t)pr[s] * 64 + d]) * w;
  }
  O[(size_t)b * o_bs + (size_t)row * 512 + h * 64 + d] = f2b(osum / lsum);
}

// ---------------- gather rows by VQ index (fp32) ----------------
__global__ __launch_bounds__(128) void gather_kernel(
    const float* __restrict__ x2, const int* __restrict__ idx, float* __restrict__ out)
{
  int t = blockIdx.x;
  int b = t >> 11;
  int code = idx[t];
  const float4* src = (const float4*)(x2 + ((size_t)(b * M_ + code) << 9));
  float4* dst = (float4*)(out + ((size_t)t << 9));
  dst[threadIdx.x] = src[threadIdx.x];
}

// ---------------- scalars ----------------
__global__ void scalars_kernel(const float* __restrict__ counts,
                               const double* __restrict__ commit_partial,
                               float* __restrict__ out_tail)
{
  int tid = threadIdx.x;
  double cs = 0.0;
#pragma unroll
  for (int i = 0; i < 8; i++) cs += commit_partial[tid + i * 1024];
  double p = (double)counts[tid] / 8192.0;
  double e = p * log(p + 1e-10);
  for (int off = 32; off; off >>= 1) {
    cs += __shfl_down(cs, off);
    e  += __shfl_down(e, off);
  }
  __shared__ double redc[16], rede[16];
  if ((tid & 63) == 0) { redc[tid >> 6] = cs; rede[tid >> 6] = e; }
  __syncthreads();
  if (tid == 0) {
    double sc = 0.0, se = 0.0;
    for (int i = 0; i < 16; i++) { sc += redc[i]; se += rede[i]; }
    out_tail[0] = (float)(sc / (8192.0 * 512.0));
    out_tail[1] = (float)exp(-se);
  }
}

extern "C" void kernel_launch(void* const* d_in, const int* in_sizes, int n_in,
                              void* d_out, int out_size, void* d_ws, size_t ws_size,
                              hipStream_t stream) {
  const float* ctx      = (const float*)d_in[0];
  const void*  mask_raw = d_in[1];
  const float* codebook = (const float*)d_in[2];
  const float* norm_g   = (const float*)d_in[3];
  const float* norm_b   = (const float*)d_in[4];
  const float* cnorm_g  = (const float*)d_in[5];
  const float* cnorm_b  = (const float*)d_in[6];
  const float* wq       = (const float*)d_in[7];
  const float* wkv      = (const float*)d_in[8];
  const float* wo       = (const float*)d_in[9];
  const float* wo_b     = (const float*)d_in[10];
  const float* a_norm_g = (const float*)d_in[11];
  const float* a_norm_b = (const float*)d_in[12];
  const float* a_qkv    = (const float*)d_in[13];
  const float* a_out    = (const float*)d_in[14];
  const float* f_norm_g = (const float*)d_in[15];
  const float* f_norm_b = (const float*)d_in[16];
  const float* f_w1     = (const float*)d_in[17];
  const float* f_w2     = (const float*)d_in[18];
  float* out = (float*)d_out;
  const float LOG2E = 1.4426950408889634f;

  char* ws = (char*)d_ws;
  int*    mask_flag  = (int*)(ws + 64);
  float*  counts     = (float*)(ws + 128);
  double* code_sq    = (double*)(ws + 4224);
  float*  csqf       = (float*)(ws + 12416);
  int*    indices    = (int*)(ws + 16512);
  int*    mask_norm  = (int*)(ws + 49280);
  int4*   cand4      = (int4*)(ws + 82048);
  double* commit_partial = (double*)(ws + 262144);

  char* pool = ws + (1 << 20);
  u16*   vqA  = (u16*)(pool);
  u16*   vqBT = (u16*)(pool + ((size_t)25 << 20));
  float4* cand_part = (float4*)(pool + ((size_t)30 << 20));
  float* attn_ml = (float*)(pool + ((size_t)61 << 20));  // free region: 61-62MB
  char* regA  = pool;
  char* regB  = pool + ((size_t)16 << 20);
  char* regC  = pool + ((size_t)24 << 20);
  char* regD  = pool + ((size_t)32 << 20);
  char* regE  = pool + ((size_t)40 << 20);
  char* regF  = pool + ((size_t)44 << 20);
  size_t woff = (1 << 20) + ((size_t)64 << 20);
  u16* wqT    = (u16*)(ws + woff); woff += (size_t)512 * 512 * 2;
  u16* wkvT   = (u16*)(ws + woff); woff += (size_t)1024 * 512 * 2;
  u16* woT    = (u16*)(ws + woff); woff += (size_t)512 * 512 * 2;
  u16* aqkvT  = (u16*)(ws + woff); woff += (size_t)1536 * 512 * 2;
  u16* aoutT  = (u16*)(ws + woff); woff += (size_t)512 * 512 * 2;
  u16* fw1T   = (u16*)(ws + woff); woff += (size_t)1024 * 512 * 2;
  u16* fw2T   = (u16*)(ws + woff); woff += (size_t)512 * 1024 * 2;
  u16* xq_b   = (u16*)(ws + woff); woff += (size_t)1024 * 512 * 2;
  u16* qs_b   = (u16*)(ws + woff); woff += (size_t)1024 * 512 * 2;

  u16* kv_b     = (u16*)regA;
  u16* qkv2_b   = (u16*)regA;
  u16* ctx_ln_b = (u16*)regB;
  u16* VtS      = (u16*)regB;
  u16* VtX      = (u16*)regC;
  float* x1_f   = (float*)regC;
  float* x0_f   = (float*)regD;
  u16* att_out_b = (u16*)regE;
  u16* h_b       = (u16*)regE;
  u16* o2_b      = (u16*)regE;
  u16* hf_b      = (u16*)regE;
  u16* g_b      = (u16*)regF;
  float* x2_f   = (float*)(pool + ((size_t)52 << 20));
  u16* attn_part = (u16*)regF;

  // ---- VQ (bf16 K=512 distance GEMM + top-4 exact refine) ----
  zero_init_kernel<<<1, 1024, 0, stream>>>(counts);
  mask_detect_kernel<<<1, 256, 0, stream>>>((const unsigned char*)mask_raw, mask_flag);
  mask_norm_kernel<<<32, 256, 0, stream>>>(mask_raw, mask_flag, mask_norm);
  code_sq_kernel<<<1024, 128, 0, stream>>>(codebook, code_sq, csqf);
  conv_bf16_kernel<<<2048, 256, 0, stream>>>(ctx, vqA);
  conv_bf16_kernel<<<256, 256, 0, stream>>>(codebook, vqBT);
  gemm_bf16_kernel<128><<<dim3(8, 64), 256, 0, stream>>>(vqA, vqBT, nullptr, nullptr,
                                                    nullptr, nullptr, csqf, cand_part,
                                                    8192, 1024, 512, 2);
  vq_top4_reduce_kernel<<<32, 256, 0, stream>>>(cand_part, cand4);
  vq_refine4_kernel<<<2048, 256, 0, stream>>>(ctx, codebook, code_sq, cand4, indices,
                                              commit_partial, counts);

  // ---- weight conversion ----
  WJobs jobs;
  jobs.src[0] = wq;    jobs.dst[0] = wqT;   jobs.K[0] = 512;  jobs.N[0] = 512;
  jobs.src[1] = wkv;   jobs.dst[1] = wkvT;  jobs.K[1] = 512;  jobs.N[1] = 1024;
  jobs.src[2] = wo;    jobs.dst[2] = woT;   jobs.K[2] = 512;  jobs.N[2] = 512;
  jobs.src[3] = a_qkv; jobs.dst[3] = aqkvT; jobs.K[3] = 512;  jobs.N[3] = 1536;
  jobs.src[4] = a_out; jobs.dst[4] = aoutT; jobs.K[4] = 512;  jobs.N[4] = 512;
  jobs.src[5] = f_w1;  jobs.dst[5] = fw1T;  jobs.K[5] = 512;  jobs.N[5] = 1024;
  jobs.src[6] = f_w2;  jobs.dst[6] = fw2T;  jobs.K[6] = 1024; jobs.N[6] = 512;
  int acc_b = 0;
  for (int i = 0; i < 7; i++) {
    jobs.b0[i] = acc_b;
    acc_b += (jobs.K[i] >> 5) * (jobs.N[i] >> 5);
  }
  jobs.b0[7] = acc_b;
  wconv_all_kernel<<<acc_b, 256, 0, stream>>>(jobs);

  // ---- Cross-attention ----
  ln_rows_kernel<<<1024, 256, 0, stream>>>(codebook, norm_g, norm_b, xq_b);
  gemm_bf16_kernel<64><<<dim3(8, 8), 256, 0, stream>>>(xq_b, wqT, nullptr, nullptr,
                                                   nullptr, qs_b, nullptr, nullptr,
                                                   1024, 512, 512, 0);
  ln_rows_kernel<<<8192, 256, 0, stream>>>(ctx, cnorm_g, cnorm_b, ctx_ln_b);
  gemm_bf16_kernel<128><<<dim3(8, 64), 256, 0, stream>>>(ctx_ln_b, wkvT, nullptr, nullptr,
                                                    nullptr, kv_b, nullptr, nullptr,
                                                    8192, 1024, 512, 0);
  vt_kernel<<<dim3(64, 32), 256, 0, stream>>>(kv_b, (size_t)2048 * 1024, 1024, 512, 2048, VtX);
  attn_mfma_kernel<<<dim3(8, 8, 16), 256, 0, stream>>>(
      qs_b, 0, 512, kv_b, (size_t)2048 * 1024, 1024, 0, VtX, mask_norm,
      0.125f * LOG2E, attn_part, attn_ml, 2048);
  attn_combine_kernel<<<8192, 256, 0, stream>>>(attn_part, attn_ml, att_out_b, (size_t)1024 * 512);
  gemm_bf16_kernel<64><<<dim3(8, 32), 256, 0, stream>>>(att_out_b, woT, wo_b, nullptr,
                                                    x0_f, nullptr, nullptr, nullptr,
                                                    4096, 512, 512, 0);

  // ---- Transformer refinement ----
  ln_rows_kernel<<<4096, 256, 0, stream>>>(x0_f, a_norm_g, a_norm_b, h_b);
  gemm_bf16_kernel<64><<<dim3(24, 32), 256, 0, stream>>>(h_b, aqkvT, nullptr, nullptr,
                                                     nullptr, qkv2_b, nullptr, nullptr,
                                                     4096, 1536, 512, 0);
  vt_kernel<<<dim3(32, 32), 256, 0, stream>>>(qkv2_b, (size_t)1024 * 1536, 1536, 1024, 1024, VtS);
  attn_mfma_kernel<<<dim3(8, 8, 16), 256, 0, stream>>>(
      qkv2_b, (size_t)1024 * 1536, 1536, qkv2_b, (size_t)1024 * 1536, 1536, 512, VtS, nullptr,
      0.125f * LOG2E, attn_part, attn_ml, 1024);
  attn_combine_kernel<<<8192, 256, 0, stream>>>(attn_part, attn_ml, o2_b, (size_t)1024 * 512);
  gemm_bf16_kernel<64><<<dim3(8, 32), 256, 0, stream>>>(o2_b, aoutT, nullptr, x0_f,
                                                    x1_f, nullptr, nullptr, nullptr,
                                                    4096, 512, 512, 0);
  ln_rows_kernel<<<4096, 256, 0, stream>>>(x1_f, f_norm_g, f_norm_b, hf_b);
  gemm_bf16_kernel<64><<<dim3(16, 32), 256, 0, stream>>>(hf_b, fw1T, nullptr, nullptr,
                                                    nullptr, g_b, nullptr, nullptr,
                                                    4096, 1024, 512, 1);
  gemm_bf16_kernel<64><<<dim3(8, 32), 256, 0, stream>>>(g_b, fw2T, nullptr, x1_f,
                                                    x2_f, nullptr, nullptr, nullptr,
                                                    4096, 512, 1024, 0);

  // ---- Gather + scalars ----
  gather_kernel<<<8192, 128, 0, stream>>>(x2_f, indices, out);
  scalars_kernel<<<1, 1024, 0, stream>>>(counts, commit_partial, out + (size_t)B_ * N_ * D_);
}

// Round 17
// 299.078 us; speedup vs baseline: 1.0737x; 1.0737x over previous
//
#include <hip/hip_runtime.h>
#include <math.h>

#define B_ 4
#define N_ 2048
#define D_ 512
#define M_ 1024
#define H_ 8
#define DH_ 64
#define I_ 512
#define FF_ 1024

typedef unsigned short u16;
typedef __attribute__((ext_vector_type(8))) short bf16x8;
typedef __attribute__((ext_vector_type(4))) float f32x4;

__device__ inline u16 f2b(float f) {           // fp32 -> bf16 RNE
  union { float f; unsigned int u; } v; v.f = f;
  unsigned int u = v.u;
  u += 0x7fffu + ((u >> 16) & 1u);
  return (u16)(u >> 16);
}
__device__ inline float b2f(u16 h) {
  union { unsigned int u; float f; } v; v.u = ((unsigned int)h) << 16;
  return v.f;
}
__device__ inline float ex2(float x) { return __builtin_amdgcn_exp2f(x); }
// packed fp32x2 -> bf16x2 (RNE), one instruction; lo -> [15:0], hi -> [31:16]
__device__ inline unsigned int cvtpk(float lo, float hi) {
  unsigned int r;
  asm("v_cvt_pk_bf16_f32 %0, %1, %2" : "=v"(r) : "v"(lo), "v"(hi));
  return r;
}

__device__ inline float gelu_f(float x) {
  float x3 = x * x * x;
  return 0.5f * x * (1.f + tanhf(0.7978845608028654f * (x + 0.044715f * x3)));
}

__device__ inline bool better(float d1, int i1, float d2, int i2) {
  return d1 < d2 || (d1 == d2 && i1 < i2);
}
__device__ inline void cswap(float& da, int& ia, float& db, int& ib) {
  if (better(db, ib, da, ia)) {
    float td = da; da = db; db = td;
    int ti = ia; ia = ib; ib = ti;
  }
}
__device__ inline void kmin(float& da, int& ia, float db, int ib) {
  if (better(db, ib, da, ia)) { da = db; ia = ib; }
}

// ---------------- fused prep: mask detect + bf16 conversions + weight transpose ----
struct WJobs {
  const float* src[7];
  u16* dst[7];
  int K[7], N[7], b0[8];
};

__global__ __launch_bounds__(256) void prep_kernel(
    const unsigned char* __restrict__ mb, int* __restrict__ flag,
    const float* __restrict__ ctx, u16* __restrict__ vqA,
    const float* __restrict__ cb, u16* __restrict__ vqBT,
    WJobs jobs)
{
  __shared__ float tile[32][33];
  __shared__ int any;
  int bid = blockIdx.x;
  int tid = threadIdx.x;
  if (bid == 0) {
    // mask dtype detection: int32 layout -> bytes at i%4!=0 are all zero
    if (tid == 0) any = 0;
    __syncthreads();
    int acc = 0;
    for (int i = tid; i < 8192; i += 256)
      if (i & 3) acc |= mb[i];
    if (acc) atomicOr(&any, 1);
    __syncthreads();
    if (tid == 0) *flag = any;
    return;
  }
  if (bid < 2049) {          // ctx fp32 -> bf16 (8192*512 elems)
    int i = ((bid - 1) * 256 + tid) * 8;
    float4 a = *(const float4*)(ctx + i);
    float4 b = *(const float4*)(ctx + i + 4);
    uint4 o;
    o.x = cvtpk(a.x, a.y); o.y = cvtpk(a.z, a.w);
    o.z = cvtpk(b.x, b.y); o.w = cvtpk(b.z, b.w);
    *(uint4*)(vqA + i) = o;
    return;
  }
  if (bid < 2305) {          // codebook fp32 -> bf16 (1024*512)
    int i = ((bid - 2049) * 256 + tid) * 8;
    float4 a = *(const float4*)(cb + i);
    float4 b = *(const float4*)(cb + i + 4);
    uint4 o;
    o.x = cvtpk(a.x, a.y); o.y = cvtpk(a.z, a.w);
    o.z = cvtpk(b.x, b.y); o.w = cvtpk(b.z, b.w);
    *(uint4*)(vqBT + i) = o;
    return;
  }
  // weight transpose jobs
  int wb = bid - 2305;
  int j = 0;
#pragma unroll
  for (int i = 1; i < 7; i++) if (wb >= jobs.b0[i]) j = i;
  int tb = wb - jobs.b0[j];
  int K = jobs.K[j], Nn = jobs.N[j];
  int tiles_x = Nn >> 5;
  int n0 = (tb % tiles_x) << 5, k0 = (tb / tiles_x) << 5;
  const float* W = jobs.src[j];
  u16* WT = jobs.dst[j];
  int ty = tid >> 5, tx = tid & 31;
#pragma unroll
  for (int i = 0; i < 4; i++)
    tile[ty + 8 * i][tx] = W[(size_t)(k0 + ty + 8 * i) * Nn + n0 + tx];
  __syncthreads();
#pragma unroll
  for (int i = 0; i < 4; i++)
    WT[(size_t)(n0 + ty + 8 * i) * K + k0 + tx] = f2b(tile[tx][ty + 8 * i]);
}

// ---------------- fused: codebook sumsq (+zero counts) + mask normalize ----------
__global__ __launch_bounds__(128) void sq_norm_kernel(
    const float* __restrict__ cb, double* __restrict__ csq, float* __restrict__ csqf,
    float* __restrict__ counts, const void* __restrict__ mraw,
    const int* __restrict__ flag, int* __restrict__ mnorm)
{
  int tid = threadIdx.x;
  if (blockIdx.x < 1024) {
    int row = blockIdx.x;
    const float4* r4 = (const float4*)(cb + (size_t)row * D_);
    float4 v = r4[tid];
    double s = (double)v.x * v.x + (double)v.y * v.y + (double)v.z * v.z + (double)v.w * v.w;
    for (int off = 32; off; off >>= 1) s += __shfl_down(s, off);
    __shared__ double red[2];
    if ((tid & 63) == 0) red[tid >> 6] = s;
    __syncthreads();
    if (tid == 0) {
      csq[row] = red[0] + red[1];
      csqf[row] = (float)(red[0] + red[1]);
      counts[row] = 0.f;
    }
    return;
  }
  int j = blockIdx.x - 1024;
  int fl = *flag;
#pragma unroll
  for (int k = 0; k < 2; k++) {
    int i = j * 256 + tid + k * 128;
    int v;
    if (fl) v = ((const unsigned char*)mraw)[i];
    else    v = ((const int*)mraw)[i];
    mnorm[i] = (v != 0) ? 1 : 0;
  }
}

// ---------------- VQ: top-4 merge (in-wave) + exact fp64 refine + commit + hist -----
__global__ __launch_bounds__(256) void vq_refine4_kernel(
    const float* __restrict__ flat, const float* __restrict__ cb,
    const double* __restrict__ csq, const float4* __restrict__ cand_part,
    int* __restrict__ out_idx, double* __restrict__ commit_partial,
    float* __restrict__ counts)
{
  int wave = threadIdx.x >> 6, lane = threadIdx.x & 63;
  int t = blockIdx.x * 4 + wave;
  // per-wave top-4 reduction over the 16 per-colblock sorted 4-lists
  int sl = lane & 15;
  float4 a = cand_part[(size_t)t * 32 + sl * 2];
  float4 bb = cand_part[(size_t)t * 32 + sl * 2 + 1];
  float d0 = a.x, d1 = a.y, d2 = bb.x, d3 = bb.y;
  int x0 = __float_as_int(a.z), x1 = __float_as_int(a.w);
  int x2 = __float_as_int(bb.z), x3 = __float_as_int(bb.w);
  for (int off = 1; off < 16; off <<= 1) {
    float e0 = __shfl_xor(d0, off), e1 = __shfl_xor(d1, off);
    float e2 = __shfl_xor(d2, off), e3 = __shfl_xor(d3, off);
    int y0 = __shfl_xor(x0, off), y1 = __shfl_xor(x1, off);
    int y2 = __shfl_xor(x2, off), y3 = __shfl_xor(x3, off);
    kmin(d0, x0, e3, y3); kmin(d1, x1, e2, y2);
    kmin(d2, x2, e1, y1); kmin(d3, x3, e0, y0);
    cswap(d0, x0, d2, x2); cswap(d1, x1, d3, x3);
    cswap(d0, x0, d1, x1); cswap(d2, x2, d3, x3);
  }
  // all lanes now hold the global top-4 (groups redundant)
  const float* x = flat + ((size_t)t << 9);
  const float* p0 = cb + ((size_t)x0 << 9);
  const float* p1 = cb + ((size_t)x1 << 9);
  const float* p2 = cb + ((size_t)x2 << 9);
  const float* p3 = cb + ((size_t)x3 << 9);
  double s0 = 0.0, s1 = 0.0, s2 = 0.0, s3 = 0.0, sx = 0.0;
#pragma unroll
  for (int i = 0; i < 8; i++) {
    int d = lane + i * 64;
    double xv = x[d];
    s0 += xv * (double)p0[d];
    s1 += xv * (double)p1[d];
    s2 += xv * (double)p2[d];
    s3 += xv * (double)p3[d];
    sx += xv * xv;
  }
  for (int off = 32; off; off >>= 1) {
    s0 += __shfl_down(s0, off);
    s1 += __shfl_down(s1, off);
    s2 += __shfl_down(s2, off);
    s3 += __shfl_down(s3, off);
    sx += __shfl_down(sx, off);
  }
  if (lane == 0) {
    double dd0 = csq[x0] - 2.0 * s0;
    double dd1 = csq[x1] - 2.0 * s1;
    double dd2 = csq[x2] - 2.0 * s2;
    double dd3 = csq[x3] - 2.0 * s3;
    int bi = x0; double bd = dd0;
    if (dd1 < bd || (dd1 == bd && x1 < bi)) { bd = dd1; bi = x1; }
    if (dd2 < bd || (dd2 == bd && x2 < bi)) { bd = dd2; bi = x2; }
    if (dd3 < bd || (dd3 == bd && x3 < bi)) { bd = dd3; bi = x3; }
    out_idx[t] = bi;
    commit_partial[t] = sx + bd;
    atomicAdd(counts + bi, 1.0f);
  }
}

// ---------------- LayerNorm (fp32 in -> bf16 out) ----------------
__global__ __launch_bounds__(256) void ln_rows_kernel(
    const float* __restrict__ x, const float* __restrict__ g,
    const float* __restrict__ b, u16* __restrict__ y)
{
  int row = blockIdx.x, tid = threadIdx.x;
  const float* xr = x + (size_t)row * D_;
  float v0 = xr[tid], v1 = xr[tid + 256];
  float s = v0 + v1;
  for (int off = 32; off; off >>= 1) s += __shfl_down(s, off);
  __shared__ float red[4];
  __shared__ float bcast[2];
  if ((tid & 63) == 0) red[tid >> 6] = s;
  __syncthreads();
  if (tid == 0) bcast[0] = (red[0] + red[1] + red[2] + red[3]) * (1.f / 512.f);
  __syncthreads();
  float mu = bcast[0];
  float d0 = v0 - mu, d1 = v1 - mu;
  float q = d0 * d0 + d1 * d1;
  for (int off = 32; off; off >>= 1) q += __shfl_down(q, off);
  if ((tid & 63) == 0) red[tid >> 6] = q;
  __syncthreads();
  if (tid == 0) bcast[1] = rsqrtf((red[0] + red[1] + red[2] + red[3]) * (1.f / 512.f) + 1e-5f);
  __syncthreads();
  float rs = bcast[1];
  u16* yr = y + (size_t)row * D_;
  yr[tid]       = f2b(d0 * rs * g[tid] + b[tid]);
  yr[tid + 256] = f2b(d1 * rs * g[tid + 256] + b[tid + 256]);
}

// ---------------- bf16 MFMA GEMM, templated tile width ----------------
template <int BN>
__global__ __launch_bounds__(256, 4) void gemm_bf16_kernel(
    const u16* __restrict__ A, const u16* __restrict__ BT,
    const float* __restrict__ bias, const float* __restrict__ resid,
    float* __restrict__ Cf, u16* __restrict__ Cb,
    const float* __restrict__ csqf, float4* __restrict__ cand_part,
    int M, int N, int K, int act)
{
  constexpr int MF = (BN == 128) ? 4 : 2;
  constexpr int ROWS_W = (BN == 128) ? 64 : 32;
  __shared__ __attribute__((aligned(16))) u16 As[2][128 * 40];
  __shared__ __attribute__((aligned(16))) u16 Bs[2][BN * 40];
  int tid = threadIdx.x;
  int lane = tid & 63, wave = tid >> 6;
  int wr = (BN == 128) ? (wave >> 1) : wave;
  int wc = (BN == 128) ? (wave & 1) : 0;
  int nwgx = gridDim.x;
  int nwg = nwgx * gridDim.y;
  int flat = blockIdx.y * nwgx + blockIdx.x;
  if ((nwg & 7) == 0) flat = (flat & 7) * (nwg >> 3) + (flat >> 3);
  int row0 = (flat / nwgx) << 7, col0 = (flat % nwgx) * BN;
  int l15 = lane & 15, l4 = lane >> 4;
  int sr = tid >> 2, skc = tid & 3;
  int soff = sr * 40 + skc * 8;
  const u16* pA0 = A + (size_t)(row0 + sr) * K + skc * 8;
  const u16* pA1 = A + (size_t)(row0 + 64 + sr) * K + skc * 8;
  const u16* pB0 = BT + (size_t)(col0 + sr) * K + skc * 8;
  const u16* pB1 = (BN == 128) ? (BT + (size_t)(col0 + 64 + sr) * K + skc * 8) : nullptr;
  f32x4 acc[MF][4] = {};
  int KT = K >> 5;
  bf16x8 ra0 = *(const bf16x8*)pA0;
  bf16x8 ra1 = *(const bf16x8*)pA1;
  bf16x8 rb0 = *(const bf16x8*)pB0;
  bf16x8 rb1;
  if constexpr (BN == 128) rb1 = *(const bf16x8*)pB1;
  *(bf16x8*)&As[0][soff] = ra0;
  *(bf16x8*)&As[0][64 * 40 + soff] = ra1;
  *(bf16x8*)&Bs[0][soff] = rb0;
  if constexpr (BN == 128) *(bf16x8*)&Bs[0][64 * 40 + soff] = rb1;
  if (KT > 1) {
    ra0 = *(const bf16x8*)(pA0 + 32);
    ra1 = *(const bf16x8*)(pA1 + 32);
    rb0 = *(const bf16x8*)(pB0 + 32);
    if constexpr (BN == 128) rb1 = *(const bf16x8*)(pB1 + 32);
  }
  for (int kt = 0; kt < KT; kt++) {
    int cur = kt & 1;
    __syncthreads();
    if (kt + 1 < KT) {
      *(bf16x8*)&As[cur ^ 1][soff] = ra0;
      *(bf16x8*)&As[cur ^ 1][64 * 40 + soff] = ra1;
      *(bf16x8*)&Bs[cur ^ 1][soff] = rb0;
      if constexpr (BN == 128) *(bf16x8*)&Bs[cur ^ 1][64 * 40 + soff] = rb1;
    }
    if (kt + 2 < KT) {
      int ko = (kt + 2) << 5;
      ra0 = *(const bf16x8*)(pA0 + ko);
      ra1 = *(const bf16x8*)(pA1 + ko);
      rb0 = *(const bf16x8*)(pB0 + ko);
      if constexpr (BN == 128) rb1 = *(const bf16x8*)(pB1 + ko);
    }
    bf16x8 af[MF], bfr[4];
#pragma unroll
    for (int m = 0; m < MF; m++)
      af[m] = *(const bf16x8*)&As[cur][(wr * ROWS_W + m * 16 + l15) * 40 + l4 * 8];
#pragma unroll
    for (int n = 0; n < 4; n++)
      bfr[n] = *(const bf16x8*)&Bs[cur][(wc * 64 + n * 16 + l15) * 40 + l4 * 8];
#pragma unroll
    for (int m = 0; m < MF; m++)
#pragma unroll
      for (int n = 0; n < 4; n++)
        acc[m][n] = __builtin_amdgcn_mfma_f32_16x16x32_bf16(af[m], bfr[n], acc[m][n], 0, 0, 0);
  }
  if constexpr (BN == 128) {
    if (act == 2) {
      float csq_l[4];
#pragma unroll
      for (int n = 0; n < 4; n++) csq_l[n] = csqf[col0 + wc * 64 + n * 16 + l15];
      int cbase = col0 + wc * 64 + l15;
      int slot = ((col0 >> 7) << 1) + wc;
#pragma unroll
      for (int m = 0; m < 4; m++) {
#pragma unroll
        for (int r = 0; r < 4; r++) {
          float d0 = csq_l[0] - 2.f * acc[m][0][r];
          float d1 = csq_l[1] - 2.f * acc[m][1][r];
          float d2 = csq_l[2] - 2.f * acc[m][2][r];
          float d3 = csq_l[3] - 2.f * acc[m][3][r];
          int x0 = cbase, x1 = cbase + 16, x2 = cbase + 32, x3 = cbase + 48;
          cswap(d0, x0, d1, x1); cswap(d2, x2, d3, x3);
          cswap(d0, x0, d2, x2); cswap(d1, x1, d3, x3);
          cswap(d1, x1, d2, x2);
          for (int off = 1; off < 16; off <<= 1) {
            float e0 = __shfl_xor(d0, off), e1 = __shfl_xor(d1, off);
            float e2 = __shfl_xor(d2, off), e3 = __shfl_xor(d3, off);
            int y0 = __shfl_xor(x0, off), y1 = __shfl_xor(x1, off);
            int y2 = __shfl_xor(x2, off), y3 = __shfl_xor(x3, off);
            kmin(d0, x0, e3, y3); kmin(d1, x1, e2, y2);
            kmin(d2, x2, e1, y1); kmin(d3, x3, e0, y0);
            cswap(d0, x0, d2, x2); cswap(d1, x1, d3, x3);
            cswap(d0, x0, d1, x1); cswap(d2, x2, d3, x3);
          }
          if (l15 == 0) {
            int row = row0 + wr * 64 + m * 16 + l4 * 4 + r;
            float4 v1, v2;
            v1.x = d0; v1.y = d1;
            v1.z = __int_as_float(x0); v1.w = __int_as_float(x1);
            v2.x = d2; v2.y = d3;
            v2.z = __int_as_float(x2); v2.w = __int_as_float(x3);
            cand_part[(size_t)row * 32 + slot * 2]     = v1;
            cand_part[(size_t)row * 32 + slot * 2 + 1] = v2;
          }
        }
      }
      return;
    }
  }
#pragma unroll
  for (int m = 0; m < MF; m++) {
#pragma unroll
    for (int n = 0; n < 4; n++) {
      int col = col0 + wc * 64 + n * 16 + l15;
      float bv = bias ? bias[col] : 0.f;
#pragma unroll
      for (int r = 0; r < 4; r++) {
        int row = row0 + wr * ROWS_W + m * 16 + l4 * 4 + r;
        float v = acc[m][n][r] + bv;
        if (act == 1) v = gelu_f(v);
        if (resid) v += resid[(size_t)row * N + col];
        if (Cf) Cf[(size_t)row * N + col] = v;
        if (Cb) Cb[(size_t)row * N + col] = f2b(v);
      }
    }
  }
}

// ---------------- V transpose: src rows -> Vt [b*8+h][64][n_rows] ----------------
__global__ __launch_bounds__(256) void vt_kernel(
    const u16* __restrict__ src, size_t b_stride, int row_stride, int col0,
    int n_rows, u16* __restrict__ dst)
{
  __shared__ __attribute__((aligned(16))) u16 tile[32][72];
  int t = threadIdx.x;
  int bh = blockIdx.y;
  int b = bh >> 3, h = bh & 7;
  int n0 = blockIdx.x * 32;
  int n = t >> 3, dc = t & 7;
  *(bf16x8*)&tile[n][dc * 8] =
      *(const bf16x8*)(src + (size_t)b * b_stride + (size_t)(n0 + n) * row_stride + col0 + h * 64 + dc * 8);
  __syncthreads();
  int d = t >> 2, ns = t & 3;
  bf16x8 o;
#pragma unroll
  for (int i = 0; i < 8; i++) o[i] = (short)tile[ns * 8 + i][d];
  *(bf16x8*)(dst + ((size_t)bh * 64 + d) * n_rows + n0 + ns * 8) = o;
}

// ---------------- MFMA flash attention: 32 q/wave, split-K 4, cvt_pk softmax ----
__global__ __launch_bounds__(256, 4) void attn_mfma_kernel(
    const u16* __restrict__ Q, size_t q_bs, int q_stride,
    const u16* __restrict__ Kp, size_t k_bs, int k_stride, int k_extra,
    const u16* __restrict__ Vt, const int* __restrict__ mask,
    float scale, u16* __restrict__ Opart, float* __restrict__ MLpart,
    int n_keys)
{
  __shared__ __attribute__((aligned(16))) u16 Ks[8 * 64 * 8];
  __shared__ __attribute__((aligned(16))) u16 Vs[8 * 64 * 8];
  __shared__ __attribute__((aligned(16))) u16 Ps[4][8 * 32 * 8];
  __shared__ float mbias[64];
  int tid = threadIdx.x, lane = tid & 63, wave = tid >> 6;
  int flat = blockIdx.x + (blockIdx.y << 3) + (blockIdx.z << 6);
  int swz = ((flat & 7) << 7) + (flat >> 3);
  int qb = swz & 7, h = (swz >> 3) & 7, z = swz >> 6;
  int b = z & 3, split = z >> 2;
  int q0 = qb * 128 + wave * 32;
  int l15 = lane & 15, l4 = lane >> 4;
  int nq = n_keys >> 2;
  int nstart = split * nq, nend = nstart + nq;

  const u16* qrow = Q + (size_t)b * q_bs + (size_t)(q0 + l15) * q_stride + h * 64 + l4 * 8;
  bf16x8 qfA0 = *(const bf16x8*)qrow;
  bf16x8 qfA1 = *(const bf16x8*)(qrow + 32);
  const u16* qrowB = qrow + 16 * q_stride;
  bf16x8 qfB0 = *(const bf16x8*)qrowB;
  bf16x8 qfB1 = *(const bf16x8*)(qrowB + 32);
  f32x4 oA[4] = {}, oB[4] = {};
  float mA = -3.0e38f, lA = 0.f, mB = -3.0e38f, lB = 0.f;
  int srow = tid >> 2, schunk = tid & 3;
  const u16* kbase = Kp + (size_t)b * k_bs + k_extra + h * 64;
  const u16* vtbase = Vt + (size_t)(b * 8 + h) * 64 * n_keys;

  bf16x8 pk0, pk1, pv0, pv1;
  int pmv = 1;
  {
    const u16* krow = kbase + (size_t)(nstart + srow) * k_stride;
    pk0 = *(const bf16x8*)(krow + schunk * 8);
    pk1 = *(const bf16x8*)(krow + (schunk + 4) * 8);
    const u16* vrow = vtbase + (size_t)srow * n_keys + nstart;
    pv0 = *(const bf16x8*)(vrow + schunk * 8);
    pv1 = *(const bf16x8*)(vrow + (schunk + 4) * 8);
    if (mask && tid < 64) pmv = mask[(size_t)b * n_keys + nstart + tid];
  }

  for (int n0 = nstart; n0 < nend; n0 += 64) {
    __syncthreads();
    *(bf16x8*)&Ks[(schunk * 64 + srow) * 8]       = pk0;
    *(bf16x8*)&Ks[((schunk + 4) * 64 + srow) * 8] = pk1;
    *(bf16x8*)&Vs[(schunk * 64 + srow) * 8]       = pv0;
    *(bf16x8*)&Vs[((schunk + 4) * 64 + srow) * 8] = pv1;
    if (tid < 64) mbias[tid] = (mask && !pmv) ? -3.0e38f : 0.f;
    __syncthreads();
    if (n0 + 64 < nend) {
      const u16* krow = kbase + (size_t)(n0 + 64 + srow) * k_stride;
      pk0 = *(const bf16x8*)(krow + schunk * 8);
      pk1 = *(const bf16x8*)(krow + (schunk + 4) * 8);
      const u16* vrow = vtbase + (size_t)srow * n_keys + n0 + 64;
      pv0 = *(const bf16x8*)(vrow + schunk * 8);
      pv1 = *(const bf16x8*)(vrow + (schunk + 4) * 8);
      if (mask && tid < 64) pmv = mask[(size_t)b * n_keys + n0 + 64 + tid];
    }
    // swapped QK^T for both query halves; K-frags read once, shared.
    f32x4 sacA[4], sacB[4];
#pragma unroll
    for (int kb = 0; kb < 4; kb++) {
      bf16x8 kf0 = *(const bf16x8*)&Ks[(l4 * 64 + kb * 16 + l15) * 8];
      bf16x8 kf1 = *(const bf16x8*)&Ks[((l4 + 4) * 64 + kb * 16 + l15) * 8];
      f32x4 za = {}, zb = {};
      za = __builtin_amdgcn_mfma_f32_16x16x32_bf16(kf0, qfA0, za, 0, 0, 0);
      sacA[kb] = __builtin_amdgcn_mfma_f32_16x16x32_bf16(kf1, qfA1, za, 0, 0, 0);
      zb = __builtin_amdgcn_mfma_f32_16x16x32_bf16(kf0, qfB0, zb, 0, 0, 0);
      sacB[kb] = __builtin_amdgcn_mfma_f32_16x16x32_bf16(kf1, qfB1, zb, 0, 0, 0);
    }
    // ---- softmax half A (query = l15) ----
    {
      float pmax = -3.0e38f;
#pragma unroll
      for (int kb = 0; kb < 4; kb++) {
        float4 bs = *(const float4*)&mbias[kb * 16 + l4 * 4];
        sacA[kb][0] = fmaf(sacA[kb][0], scale, bs.x);
        sacA[kb][1] = fmaf(sacA[kb][1], scale, bs.y);
        sacA[kb][2] = fmaf(sacA[kb][2], scale, bs.z);
        sacA[kb][3] = fmaf(sacA[kb][3], scale, bs.w);
#pragma unroll
        for (int r = 0; r < 4; r++) pmax = fmaxf(pmax, sacA[kb][r]);
      }
      pmax = fmaxf(pmax, __shfl_xor(pmax, 16));
      pmax = fmaxf(pmax, __shfl_xor(pmax, 32));
      if (!__all(pmax - mA <= 11.5f)) {
        float mnew = fmaxf(mA, pmax);
        float al = ex2(mA - mnew);
        lA *= al;
        mA = mnew;
        float alr[4];
#pragma unroll
        for (int r = 0; r < 4; r++) alr[r] = __shfl(al, l4 * 4 + r, 64);
#pragma unroll
        for (int nb = 0; nb < 4; nb++)
#pragma unroll
          for (int r = 0; r < 4; r++) oA[nb][r] *= alr[r];
      }
      float psum = 0.f;
#pragma unroll
      for (int kb = 0; kb < 4; kb++) {
        float p0 = ex2(sacA[kb][0] - mA);
        float p1 = ex2(sacA[kb][1] - mA);
        float p2 = ex2(sacA[kb][2] - mA);
        float p3 = ex2(sacA[kb][3] - mA);
        psum += (p0 + p1) + (p2 + p3);
        uint2 w;
        w.x = cvtpk(p0, p1);
        w.y = cvtpk(p2, p3);
        *(uint2*)&Ps[wave][((kb * 2 + (l4 >> 1)) * 32 + l15) * 8 + (l4 & 1) * 4] = w;
      }
      psum += __shfl_xor(psum, 16);
      psum += __shfl_xor(psum, 32);
      lA += psum;
    }
    // ---- softmax half B (query = 16 + l15) ----
    {
      float pmax = -3.0e38f;
#pragma unroll
      for (int kb = 0; kb < 4; kb++) {
        float4 bs = *(const float4*)&mbias[kb * 16 + l4 * 4];
        sacB[kb][0] = fmaf(sacB[kb][0], scale, bs.x);
        sacB[kb][1] = fmaf(sacB[kb][1], scale, bs.y);
        sacB[kb][2] = fmaf(sacB[kb][2], scale, bs.z);
        sacB[kb][3] = fmaf(sacB[kb][3], scale, bs.w);
#pragma unroll
        for (int r = 0; r < 4; r++) pmax = fmaxf(pmax, sacB[kb][r]);
      }
      pmax = fmaxf(pmax, __shfl_xor(pmax, 16));
      pmax = fmaxf(pmax, __shfl_xor(pmax, 32));
      if (!__all(pmax - mB <= 11.5f)) {
        float mnew = fmaxf(mB, pmax);
        float al = ex2(mB - mnew);
        lB *= al;
        mB = mnew;
        float alr[4];
#pragma unroll
        for (int r = 0; r < 4; r++) alr[r] = __shfl(al, l4 * 4 + r, 64);
#pragma unroll
        for (int nb = 0; nb < 4; nb++)
#pragma unroll
          for (int r = 0; r < 4; r++) oB[nb][r] *= alr[r];
      }
      float psum = 0.f;
#pragma unroll
      for (int kb = 0; kb < 4; kb++) {
        float p0 = ex2(sacB[kb][0] - mB);
        float p1 = ex2(sacB[kb][1] - mB);
        float p2 = ex2(sacB[kb][2] - mB);
        float p3 = ex2(sacB[kb][3] - mB);
        psum += (p0 + p1) + (p2 + p3);
        uint2 w;
        w.x = cvtpk(p0, p1);
        w.y = cvtpk(p2, p3);
        *(uint2*)&Ps[wave][((kb * 2 + (l4 >> 1)) * 32 + 16 + l15) * 8 + (l4 & 1) * 4] = w;
      }
      psum += __shfl_xor(psum, 16);
      psum += __shfl_xor(psum, 32);
      lB += psum;
    }
    // ---- PV: V-frags read once, shared by both halves ----
#pragma unroll
    for (int c = 0; c < 2; c++) {
      bf16x8 pfA = *(const bf16x8*)&Ps[wave][((c * 4 + l4) * 32 + l15) * 8];
      bf16x8 pfB = *(const bf16x8*)&Ps[wave][((c * 4 + l4) * 32 + 16 + l15) * 8];
#pragma unroll
      for (int nb = 0; nb < 4; nb++) {
        bf16x8 vf = *(const bf16x8*)&Vs[((c * 4 + l4) * 64 + nb * 16 + l15) * 8];
        oA[nb] = __builtin_amdgcn_mfma_f32_16x16x32_bf16(pfA, vf, oA[nb], 0, 0, 0);
        oB[nb] = __builtin_amdgcn_mfma_f32_16x16x32_bf16(pfB, vf, oB[nb], 0, 0, 0);
      }
    }
  }
  int pr_base = ((split * 4 + b) * 8 + h) * 1024;
#pragma unroll
  for (int nb = 0; nb < 4; nb++)
#pragma unroll
    for (int r = 0; r < 4; r++) {
      Opart[(size_t)(pr_base + q0 + l4 * 4 + r) * 64 + nb * 16 + l15] = f2b(oA[nb][r]);
      Opart[(size_t)(pr_base + q0 + 16 + l4 * 4 + r) * 64 + nb * 16 + l15] = f2b(oB[nb][r]);
    }
  if (lane < 16) {
    int pr = pr_base + q0 + lane;
    MLpart[2 * pr]     = mA;
    MLpart[2 * pr + 1] = lA;
  } else if (lane < 32) {
    int pr = pr_base + q0 + 16 + l15;
    MLpart[2 * pr]     = mB;
    MLpart[2 * pr + 1] = lB;
  }
}

// ---------------- combine the 4 split-K partials (base-2 weights) ----------------
__global__ __launch_bounds__(256) void attn_combine_kernel(
    const u16* __restrict__ Opart, const float* __restrict__ MLpart,
    u16* __restrict__ O, size_t o_bs)
{
  int idx = blockIdx.x * 256 + threadIdx.x;
  int d = idx & 63, gq = idx >> 6;
  int row = gq & 1023, bh = gq >> 10;
  int h = bh & 7, b = bh >> 3;
  float m[4], l[4];
  int pr[4];
#pragma unroll
  for (int s = 0; s < 4; s++) {
    pr[s] = ((s * 4 + b) * 8 + h) * 1024 + row;
    m[s] = MLpart[2 * pr[s]];
    l[s] = MLpart[2 * pr[s] + 1];
  }
  float mmax = fmaxf(fmaxf(m[0], m[1]), fmaxf(m[2], m[3]));
  float lsum = 0.f, osum = 0.f;
#pragma unroll
  for (int s = 0; s < 4; s++) {
    float w = ex2(m[s] - mmax);
    lsum += l[s] * w;
    osum += b2f(Opart[(size_t)pr[s] * 64 + d]) * w;
  }
  O[(size_t)b * o_bs + (size_t)row * 512 + h * 64 + d] = f2b(osum / lsum);
}

// ---------------- fused gather + scalars ----------------
__global__ __launch_bounds__(128) void gather_scalars_kernel(
    const float* __restrict__ x2, const int* __restrict__ idx,
    const float* __restrict__ counts, const double* __restrict__ commit_partial,
    float* __restrict__ out, float* __restrict__ out_tail)
{
  int t = blockIdx.x;
  int tid = threadIdx.x;
  if (t < 8192) {
    int b = t >> 11;
    int code = idx[t];
    const float4* src = (const float4*)(x2 + ((size_t)(b * M_ + code) << 9));
    float4* dst = (float4*)(out + ((size_t)t << 9));
    dst[tid] = src[tid];
    return;
  }
  // scalars: commit loss + perplexity (128 threads)
  double cs = 0.0;
#pragma unroll
  for (int i = 0; i < 64; i++) cs += commit_partial[tid + i * 128];
  double e = 0.0;
#pragma unroll
  for (int i = 0; i < 8; i++) {
    double p = (double)counts[tid + i * 128] / 8192.0;
    e += p * log(p + 1e-10);
  }
  for (int off = 32; off; off >>= 1) {
    cs += __shfl_down(cs, off);
    e  += __shfl_down(e, off);
  }
  __shared__ double redc[2], rede[2];
  if ((tid & 63) == 0) { redc[tid >> 6] = cs; rede[tid >> 6] = e; }
  __syncthreads();
  if (tid == 0) {
    out_tail[0] = (float)((redc[0] + redc[1]) / (8192.0 * 512.0));
    out_tail[1] = (float)exp(-(rede[0] + rede[1]));
  }
}

extern "C" void kernel_launch(void* const* d_in, const int* in_sizes, int n_in,
                              void* d_out, int out_size, void* d_ws, size_t ws_size,
                              hipStream_t stream) {
  const float* ctx      = (const float*)d_in[0];
  const void*  mask_raw = d_in[1];
  const float* codebook = (const float*)d_in[2];
  const float* norm_g   = (const float*)d_in[3];
  const float* norm_b   = (const float*)d_in[4];
  const float* cnorm_g  = (const float*)d_in[5];
  const float* cnorm_b  = (const float*)d_in[6];
  const float* wq       = (const float*)d_in[7];
  const float* wkv      = (const float*)d_in[8];
  const float* wo       = (const float*)d_in[9];
  const float* wo_b     = (const float*)d_in[10];
  const float* a_norm_g = (const float*)d_in[11];
  const float* a_norm_b = (const float*)d_in[12];
  const float* a_qkv    = (const float*)d_in[13];
  const float* a_out    = (const float*)d_in[14];
  const float* f_norm_g = (const float*)d_in[15];
  const float* f_norm_b = (const float*)d_in[16];
  const float* f_w1     = (const float*)d_in[17];
  const float* f_w2     = (const float*)d_in[18];
  float* out = (float*)d_out;
  const float LOG2E = 1.4426950408889634f;

  char* ws = (char*)d_ws;
  int*    mask_flag  = (int*)(ws + 64);
  float*  counts     = (float*)(ws + 128);
  double* code_sq    = (double*)(ws + 4224);
  float*  csqf       = (float*)(ws + 12416);
  int*    indices    = (int*)(ws + 16512);
  int*    mask_norm  = (int*)(ws + 49280);
  double* commit_partial = (double*)(ws + 262144);

  char* pool = ws + (1 << 20);
  u16*   vqA  = (u16*)(pool);
  u16*   vqBT = (u16*)(pool + ((size_t)25 << 20));
  float4* cand_part = (float4*)(pool + ((size_t)30 << 20));
  float* attn_ml = (float*)(pool + ((size_t)61 << 20));  // free region: 61-62MB
  char* regA  = pool;
  char* regB  = pool + ((size_t)16 << 20);
  char* regC  = pool + ((size_t)24 << 20);
  char* regD  = pool + ((size_t)32 << 20);
  char* regE  = pool + ((size_t)40 << 20);
  char* regF  = pool + ((size_t)44 << 20);
  size_t woff = (1 << 20) + ((size_t)64 << 20);
  u16* wqT    = (u16*)(ws + woff); woff += (size_t)512 * 512 * 2;
  u16* wkvT   = (u16*)(ws + woff); woff += (size_t)1024 * 512 * 2;
  u16* woT    = (u16*)(ws + woff); woff += (size_t)512 * 512 * 2;
  u16* aqkvT  = (u16*)(ws + woff); woff += (size_t)1536 * 512 * 2;
  u16* aoutT  = (u16*)(ws + woff); woff += (size_t)512 * 512 * 2;
  u16* fw1T   = (u16*)(ws + woff); woff += (size_t)1024 * 512 * 2;
  u16* fw2T   = (u16*)(ws + woff); woff += (size_t)512 * 1024 * 2;
  u16* xq_b   = (u16*)(ws + woff); woff += (size_t)1024 * 512 * 2;
  u16* qs_b   = (u16*)(ws + woff); woff += (size_t)1024 * 512 * 2;

  u16* kv_b     = (u16*)regA;
  u16* qkv2_b   = (u16*)regA;
  u16* ctx_ln_b = (u16*)regB;
  u16* VtS      = (u16*)regB;
  u16* VtX      = (u16*)regC;
  float* x1_f   = (float*)regC;
  float* x0_f   = (float*)regD;
  u16* att_out_b = (u16*)regE;
  u16* h_b       = (u16*)regE;
  u16* o2_b      = (u16*)regE;
  u16* hf_b      = (u16*)regE;
  u16* g_b      = (u16*)regF;
  float* x2_f   = (float*)(pool + ((size_t)52 << 20));
  u16* attn_part = (u16*)regF;

  // ---- fused prep: detect + bf16 conversions + weight transposes (1 launch) ----
  WJobs jobs;
  jobs.src[0] = wq;    jobs.dst[0] = wqT;   jobs.K[0] = 512;  jobs.N[0] = 512;
  jobs.src[1] = wkv;   jobs.dst[1] = wkvT;  jobs.K[1] = 512;  jobs.N[1] = 1024;
  jobs.src[2] = wo;    jobs.dst[2] = woT;   jobs.K[2] = 512;  jobs.N[2] = 512;
  jobs.src[3] = a_qkv; jobs.dst[3] = aqkvT; jobs.K[3] = 512;  jobs.N[3] = 1536;
  jobs.src[4] = a_out; jobs.dst[4] = aoutT; jobs.K[4] = 512;  jobs.N[4] = 512;
  jobs.src[5] = f_w1;  jobs.dst[5] = fw1T;  jobs.K[5] = 512;  jobs.N[5] = 1024;
  jobs.src[6] = f_w2;  jobs.dst[6] = fw2T;  jobs.K[6] = 1024; jobs.N[6] = 512;
  int acc_b = 0;
  for (int i = 0; i < 7; i++) {
    jobs.b0[i] = acc_b;
    acc_b += (jobs.K[i] >> 5) * (jobs.N[i] >> 5);
  }
  jobs.b0[7] = acc_b;
  prep_kernel<<<2305 + acc_b, 256, 0, stream>>>(
      (const unsigned char*)mask_raw, mask_flag, ctx, vqA, codebook, vqBT, jobs);

  // ---- code_sq (+zero counts) + mask normalize (1 launch) ----
  sq_norm_kernel<<<1056, 128, 0, stream>>>(codebook, code_sq, csqf, counts,
                                           mask_raw, mask_flag, mask_norm);

  // ---- VQ distance GEMM + fused top4/refine ----
  gemm_bf16_kernel<128><<<dim3(8, 64), 256, 0, stream>>>(vqA, vqBT, nullptr, nullptr,
                                                    nullptr, nullptr, csqf, cand_part,
                                                    8192, 1024, 512, 2);
  vq_refine4_kernel<<<2048, 256, 0, stream>>>(ctx, codebook, code_sq, cand_part, indices,
                                              commit_partial, counts);

  // ---- Cross-attention ----
  ln_rows_kernel<<<1024, 256, 0, stream>>>(codebook, norm_g, norm_b, xq_b);
  gemm_bf16_kernel<64><<<dim3(8, 8), 256, 0, stream>>>(xq_b, wqT, nullptr, nullptr,
                                                   nullptr, qs_b, nullptr, nullptr,
                                                   1024, 512, 512, 0);
  ln_rows_kernel<<<8192, 256, 0, stream>>>(ctx, cnorm_g, cnorm_b, ctx_ln_b);
  gemm_bf16_kernel<128><<<dim3(8, 64), 256, 0, stream>>>(ctx_ln_b, wkvT, nullptr, nullptr,
                                                    nullptr, kv_b, nullptr, nullptr,
                                                    8192, 1024, 512, 0);
  vt_kernel<<<dim3(64, 32), 256, 0, stream>>>(kv_b, (size_t)2048 * 1024, 1024, 512, 2048, VtX);
  attn_mfma_kernel<<<dim3(8, 8, 16), 256, 0, stream>>>(
      qs_b, 0, 512, kv_b, (size_t)2048 * 1024, 1024, 0, VtX, mask_norm,
      0.125f * LOG2E, attn_part, attn_ml, 2048);
  attn_combine_kernel<<<8192, 256, 0, stream>>>(attn_part, attn_ml, att_out_b, (size_t)1024 * 512);
  gemm_bf16_kernel<64><<<dim3(8, 32), 256, 0, stream>>>(att_out_b, woT, wo_b, nullptr,
                                                    x0_f, nullptr, nullptr, nullptr,
                                                    4096, 512, 512, 0);

  // ---- Transformer refinement ----
  ln_rows_kernel<<<4096, 256, 0, stream>>>(x0_f, a_norm_g, a_norm_b, h_b);
  gemm_bf16_kernel<64><<<dim3(24, 32), 256, 0, stream>>>(h_b, aqkvT, nullptr, nullptr,
                                                     nullptr, qkv2_b, nullptr, nullptr,
                                                     4096, 1536, 512, 0);
  vt_kernel<<<dim3(32, 32), 256, 0, stream>>>(qkv2_b, (size_t)1024 * 1536, 1536, 1024, 1024, VtS);
  attn_mfma_kernel<<<dim3(8, 8, 16), 256, 0, stream>>>(
      qkv2_b, (size_t)1024 * 1536, 1536, qkv2_b, (size_t)1024 * 1536, 1536, 512, VtS, nullptr,
      0.125f * LOG2E, attn_part, attn_ml, 1024);
  attn_combine_kernel<<<8192, 256, 0, stream>>>(attn_part, attn_ml, o2_b, (size_t)1024 * 512);
  gemm_bf16_kernel<64><<<dim3(8, 32), 256, 0, stream>>>(o2_b, aoutT, nullptr, x0_f,
                                                    x1_f, nullptr, nullptr, nullptr,
                                                    4096, 512, 512, 0);
  ln_rows_kernel<<<4096, 256, 0, stream>>>(x1_f, f_norm_g, f_norm_b, hf_b);
  gemm_bf16_kernel<64><<<dim3(16, 32), 256, 0, stream>>>(hf_b, fw1T, nullptr, nullptr,
                                                    nullptr, g_b, nullptr, nullptr,
                                                    4096, 1024, 512, 1);
  gemm_bf16_kernel<64><<<dim3(8, 32), 256, 0, stream>>>(g_b, fw2T, nullptr, x1_f,
                                                    x2_f, nullptr, nullptr, nullptr,
                                                    4096, 512, 1024, 0);

  // ---- fused gather + scalars ----
  gather_scalars_kernel<<<8193, 128, 0, stream>>>(x2_f, indices, counts, commit_partial,
                                                  out, out + (size_t)B_ * N_ * D_);
}

// Round 19
// 295.853 us; speedup vs baseline: 1.0854x; 1.0109x over previous
//
#include <hip/hip_runtime.h>
#include <math.h>

#define B_ 4
#define N_ 2048
#define D_ 512
#define M_ 1024
#define H_ 8
#define DH_ 64
#define I_ 512
#define FF_ 1024

typedef unsigned short u16;
typedef __attribute__((ext_vector_type(8))) short bf16x8;
typedef __attribute__((ext_vector_type(4))) float f32x4;

__device__ inline u16 f2b(float f) {           // fp32 -> bf16 RNE
  union { float f; unsigned int u; } v; v.f = f;
  unsigned int u = v.u;
  u += 0x7fffu + ((u >> 16) & 1u);
  return (u16)(u >> 16);
}
__device__ inline float b2f(u16 h) {
  union { unsigned int u; float f; } v; v.u = ((unsigned int)h) << 16;
  return v.f;
}
__device__ inline float ex2(float x) { return __builtin_amdgcn_exp2f(x); }
__device__ inline unsigned int cvtpk(float lo, float hi) {
  unsigned int r;
  asm("v_cvt_pk_bf16_f32 %0, %1, %2" : "=v"(r) : "v"(lo), "v"(hi));
  return r;
}

__device__ inline float gelu_f(float x) {
  float x3 = x * x * x;
  return 0.5f * x * (1.f + tanhf(0.7978845608028654f * (x + 0.044715f * x3)));
}

__device__ inline bool better(float d1, int i1, float d2, int i2) {
  return d1 < d2 || (d1 == d2 && i1 < i2);
}
__device__ inline void cswap(float& da, int& ia, float& db, int& ib) {
  if (better(db, ib, da, ia)) {
    float td = da; da = db; db = td;
    int ti = ia; ia = ib; ib = ti;
  }
}
__device__ inline void kmin(float& da, int& ia, float db, int ib) {
  if (better(db, ib, da, ia)) { da = db; ia = ib; }
}

// ---------------- mega prep: detect+masknorm, convs, code_sq, input LNs, wconv ----
struct WJobs {
  const float* src[7];
  u16* dst[7];
  int K[7], N[7], b0[8];
};

__global__ __launch_bounds__(256) void prep_kernel(
    const void* __restrict__ mraw, int* __restrict__ mnorm,
    const float* __restrict__ ctx, u16* __restrict__ vqA,
    const float* __restrict__ cb, u16* __restrict__ vqBT,
    const float* __restrict__ norm_g, const float* __restrict__ norm_b,
    u16* __restrict__ xq_b,
    const float* __restrict__ cnorm_g, const float* __restrict__ cnorm_b,
    u16* __restrict__ ctx_ln_b,
    double* __restrict__ csq, float* __restrict__ csqf, float* __restrict__ counts,
    WJobs jobs)
{
  __shared__ float tile[32][33];
  __shared__ int any;
  __shared__ float redf[4];
  __shared__ float bc[2];
  __shared__ double redd[4];
  int bid = blockIdx.x;
  int tid = threadIdx.x;
  const unsigned char* mb = (const unsigned char*)mraw;
  if (bid == 0) {
    if (tid == 0) any = 0;
    __syncthreads();
    int acc = 0;
    for (int i = tid; i < 8192; i += 256)
      if (i & 3) acc |= mb[i];
    if (acc) atomicOr(&any, 1);
    __syncthreads();
    int fl = any;
    for (int i = tid; i < 8192; i += 256) {
      int v = fl ? mb[i] : ((const int*)mraw)[i];
      mnorm[i] = (v != 0) ? 1 : 0;
    }
    return;
  }
  if (bid < 2049) {          // ctx fp32 -> bf16
    int i = ((bid - 1) * 256 + tid) * 8;
    float4 a = *(const float4*)(ctx + i);
    float4 b = *(const float4*)(ctx + i + 4);
    uint4 o;
    o.x = cvtpk(a.x, a.y); o.y = cvtpk(a.z, a.w);
    o.z = cvtpk(b.x, b.y); o.w = cvtpk(b.z, b.w);
    *(uint4*)(vqA + i) = o;
    return;
  }
  if (bid < 2305) {          // codebook fp32 -> bf16
    int i = ((bid - 2049) * 256 + tid) * 8;
    float4 a = *(const float4*)(cb + i);
    float4 b = *(const float4*)(cb + i + 4);
    uint4 o;
    o.x = cvtpk(a.x, a.y); o.y = cvtpk(a.z, a.w);
    o.z = cvtpk(b.x, b.y); o.w = cvtpk(b.z, b.w);
    *(uint4*)(vqBT + i) = o;
    return;
  }
  if (bid < 3329) {          // codebook row sum-of-squares + counts zero
    int row = bid - 2305;
    float2 v = ((const float2*)(cb + (size_t)row * D_))[tid];
    double s = (double)v.x * v.x + (double)v.y * v.y;
    for (int off = 32; off; off >>= 1) s += __shfl_down(s, off);
    if ((tid & 63) == 0) redd[tid >> 6] = s;
    __syncthreads();
    if (tid == 0) {
      double t = redd[0] + redd[1] + redd[2] + redd[3];
      csq[row] = t;
      csqf[row] = (float)t;
      counts[row] = 0.f;
    }
    return;
  }
  if (bid < 12545) {         // LayerNorm: codebook rows (3329..4352) / ctx rows (4353..)
    int row;
    const float* xr;
    const float* g;
    const float* bb;
    u16* yr;
    if (bid < 4353) {
      row = bid - 3329;
      xr = cb + (size_t)row * D_;
      g = norm_g; bb = norm_b;
      yr = xq_b + (size_t)row * D_;
    } else {
      row = bid - 4353;
      xr = ctx + (size_t)row * D_;
      g = cnorm_g; bb = cnorm_b;
      yr = ctx_ln_b + (size_t)row * D_;
    }
    float v0 = xr[tid], v1 = xr[tid + 256];
    float s = v0 + v1;
    for (int off = 32; off; off >>= 1) s += __shfl_down(s, off);
    if ((tid & 63) == 0) redf[tid >> 6] = s;
    __syncthreads();
    if (tid == 0) bc[0] = (redf[0] + redf[1] + redf[2] + redf[3]) * (1.f / 512.f);
    __syncthreads();
    float mu = bc[0];
    float d0 = v0 - mu, d1 = v1 - mu;
    float q = d0 * d0 + d1 * d1;
    for (int off = 32; off; off >>= 1) q += __shfl_down(q, off);
    if ((tid & 63) == 0) redf[tid >> 6] = q;
    __syncthreads();
    if (tid == 0) bc[1] = rsqrtf((redf[0] + redf[1] + redf[2] + redf[3]) * (1.f / 512.f) + 1e-5f);
    __syncthreads();
    float rs = bc[1];
    yr[tid]       = f2b(d0 * rs * g[tid] + bb[tid]);
    yr[tid + 256] = f2b(d1 * rs * g[tid + 256] + bb[tid + 256]);
    return;
  }
  // weight transpose jobs
  int wb = bid - 12545;
  int j = 0;
#pragma unroll
  for (int i = 1; i < 7; i++) if (wb >= jobs.b0[i]) j = i;
  int tb = wb - jobs.b0[j];
  int K = jobs.K[j], Nn = jobs.N[j];
  int tiles_x = Nn >> 5;
  int n0 = (tb % tiles_x) << 5, k0 = (tb / tiles_x) << 5;
  const float* W = jobs.src[j];
  u16* WT = jobs.dst[j];
  int ty = tid >> 5, tx = tid & 31;
#pragma unroll
  for (int i = 0; i < 4; i++)
    tile[ty + 8 * i][tx] = W[(size_t)(k0 + ty + 8 * i) * Nn + n0 + tx];
  __syncthreads();
#pragma unroll
  for (int i = 0; i < 4; i++)
    WT[(size_t)(n0 + ty + 8 * i) * K + k0 + tx] = f2b(tile[tx][ty + 8 * i]);
}

// ---------------- VQ: top-4 merge (in-wave) + exact fp64 refine + commit + hist -----
__global__ __launch_bounds__(256) void vq_refine4_kernel(
    const float* __restrict__ flat, const float* __restrict__ cb,
    const double* __restrict__ csq, const float4* __restrict__ cand_part,
    int* __restrict__ out_idx, double* __restrict__ commit_partial,
    float* __restrict__ counts)
{
  int wave = threadIdx.x >> 6, lane = threadIdx.x & 63;
  int t = blockIdx.x * 4 + wave;
  int sl = lane & 15;
  float4 a = cand_part[(size_t)t * 32 + sl * 2];
  float4 bb = cand_part[(size_t)t * 32 + sl * 2 + 1];
  float d0 = a.x, d1 = a.y, d2 = bb.x, d3 = bb.y;
  int x0 = __float_as_int(a.z), x1 = __float_as_int(a.w);
  int x2 = __float_as_int(bb.z), x3 = __float_as_int(bb.w);
  for (int off = 1; off < 16; off <<= 1) {
    float e0 = __shfl_xor(d0, off), e1 = __shfl_xor(d1, off);
    float e2 = __shfl_xor(d2, off), e3 = __shfl_xor(d3, off);
    int y0 = __shfl_xor(x0, off), y1 = __shfl_xor(x1, off);
    int y2 = __shfl_xor(x2, off), y3 = __shfl_xor(x3, off);
    kmin(d0, x0, e3, y3); kmin(d1, x1, e2, y2);
    kmin(d2, x2, e1, y1); kmin(d3, x3, e0, y0);
    cswap(d0, x0, d2, x2); cswap(d1, x1, d3, x3);
    cswap(d0, x0, d1, x1); cswap(d2, x2, d3, x3);
  }
  const float* x = flat + ((size_t)t << 9);
  const float* p0 = cb + ((size_t)x0 << 9);
  const float* p1 = cb + ((size_t)x1 << 9);
  const float* p2 = cb + ((size_t)x2 << 9);
  const float* p3 = cb + ((size_t)x3 << 9);
  double s0 = 0.0, s1 = 0.0, s2 = 0.0, s3 = 0.0, sx = 0.0;
#pragma unroll
  for (int i = 0; i < 8; i++) {
    int d = lane + i * 64;
    double xv = x[d];
    s0 += xv * (double)p0[d];
    s1 += xv * (double)p1[d];
    s2 += xv * (double)p2[d];
    s3 += xv * (double)p3[d];
    sx += xv * xv;
  }
  for (int off = 32; off; off >>= 1) {
    s0 += __shfl_down(s0, off);
    s1 += __shfl_down(s1, off);
    s2 += __shfl_down(s2, off);
    s3 += __shfl_down(s3, off);
    sx += __shfl_down(sx, off);
  }
  if (lane == 0) {
    double dd0 = csq[x0] - 2.0 * s0;
    double dd1 = csq[x1] - 2.0 * s1;
    double dd2 = csq[x2] - 2.0 * s2;
    double dd3 = csq[x3] - 2.0 * s3;
    int bi = x0; double bd = dd0;
    if (dd1 < bd || (dd1 == bd && x1 < bi)) { bd = dd1; bi = x1; }
    if (dd2 < bd || (dd2 == bd && x2 < bi)) { bd = dd2; bi = x2; }
    if (dd3 < bd || (dd3 == bd && x3 < bi)) { bd = dd3; bi = x3; }
    out_idx[t] = bi;
    commit_partial[t] = sx + bd;
    atomicAdd(counts + bi, 1.0f);
  }
}

// ---------------- LayerNorm (fp32 in -> bf16 out) — mid-pipeline uses ----------
__global__ __launch_bounds__(256) void ln_rows_kernel(
    const float* __restrict__ x, const float* __restrict__ g,
    const float* __restrict__ b, u16* __restrict__ y)
{
  int row = blockIdx.x, tid = threadIdx.x;
  const float* xr = x + (size_t)row * D_;
  float v0 = xr[tid], v1 = xr[tid + 256];
  float s = v0 + v1;
  for (int off = 32; off; off >>= 1) s += __shfl_down(s, off);
  __shared__ float red[4];
  __shared__ float bcast[2];
  if ((tid & 63) == 0) red[tid >> 6] = s;
  __syncthreads();
  if (tid == 0) bcast[0] = (red[0] + red[1] + red[2] + red[3]) * (1.f / 512.f);
  __syncthreads();
  float mu = bcast[0];
  float d0 = v0 - mu, d1 = v1 - mu;
  float q = d0 * d0 + d1 * d1;
  for (int off = 32; off; off >>= 1) q += __shfl_down(q, off);
  if ((tid & 63) == 0) red[tid >> 6] = q;
  __syncthreads();
  if (tid == 0) bcast[1] = rsqrtf((red[0] + red[1] + red[2] + red[3]) * (1.f / 512.f) + 1e-5f);
  __syncthreads();
  float rs = bcast[1];
  u16* yr = y + (size_t)row * D_;
  yr[tid]       = f2b(d0 * rs * g[tid] + b[tid]);
  yr[tid + 256] = f2b(d1 * rs * g[tid + 256] + b[tid + 256]);
}

// ---------------- bf16 MFMA GEMM, templated tile width ----------------
template <int BN>
__global__ __launch_bounds__(256, 4) void gemm_bf16_kernel(
    const u16* __restrict__ A, const u16* __restrict__ BT,
    const float* __restrict__ bias, const float* __restrict__ resid,
    float* __restrict__ Cf, u16* __restrict__ Cb,
    const float* __restrict__ csqf, float4* __restrict__ cand_part,
    int M, int N, int K, int act)
{
  constexpr int MF = (BN == 128) ? 4 : 2;
  constexpr int ROWS_W = (BN == 128) ? 64 : 32;
  __shared__ __attribute__((aligned(16))) u16 As[2][128 * 40];
  __shared__ __attribute__((aligned(16))) u16 Bs[2][BN * 40];
  int tid = threadIdx.x;
  int lane = tid & 63, wave = tid >> 6;
  int wr = (BN == 128) ? (wave >> 1) : wave;
  int wc = (BN == 128) ? (wave & 1) : 0;
  int nwgx = gridDim.x;
  int nwg = nwgx * gridDim.y;
  int flat = blockIdx.y * nwgx + blockIdx.x;
  if ((nwg & 7) == 0) flat = (flat & 7) * (nwg >> 3) + (flat >> 3);
  int row0 = (flat / nwgx) << 7, col0 = (flat % nwgx) * BN;
  int l15 = lane & 15, l4 = lane >> 4;
  int sr = tid >> 2, skc = tid & 3;
  int soff = sr * 40 + skc * 8;
  const u16* pA0 = A + (size_t)(row0 + sr) * K + skc * 8;
  const u16* pA1 = A + (size_t)(row0 + 64 + sr) * K + skc * 8;
  const u16* pB0 = BT + (size_t)(col0 + sr) * K + skc * 8;
  const u16* pB1 = (BN == 128) ? (BT + (size_t)(col0 + 64 + sr) * K + skc * 8) : nullptr;
  f32x4 acc[MF][4] = {};
  int KT = K >> 5;
  bf16x8 ra0 = *(const bf16x8*)pA0;
  bf16x8 ra1 = *(const bf16x8*)pA1;
  bf16x8 rb0 = *(const bf16x8*)pB0;
  bf16x8 rb1;
  if constexpr (BN == 128) rb1 = *(const bf16x8*)pB1;
  *(bf16x8*)&As[0][soff] = ra0;
  *(bf16x8*)&As[0][64 * 40 + soff] = ra1;
  *(bf16x8*)&Bs[0][soff] = rb0;
  if constexpr (BN == 128) *(bf16x8*)&Bs[0][64 * 40 + soff] = rb1;
  if (KT > 1) {
    ra0 = *(const bf16x8*)(pA0 + 32);
    ra1 = *(const bf16x8*)(pA1 + 32);
    rb0 = *(const bf16x8*)(pB0 + 32);
    if constexpr (BN == 128) rb1 = *(const bf16x8*)(pB1 + 32);
  }
  for (int kt = 0; kt < KT; kt++) {
    int cur = kt & 1;
    __syncthreads();
    if (kt + 1 < KT) {
      *(bf16x8*)&As[cur ^ 1][soff] = ra0;
      *(bf16x8*)&As[cur ^ 1][64 * 40 + soff] = ra1;
      *(bf16x8*)&Bs[cur ^ 1][soff] = rb0;
      if constexpr (BN == 128) *(bf16x8*)&Bs[cur ^ 1][64 * 40 + soff] = rb1;
    }
    if (kt + 2 < KT) {
      int ko = (kt + 2) << 5;
      ra0 = *(const bf16x8*)(pA0 + ko);
      ra1 = *(const bf16x8*)(pA1 + ko);
      rb0 = *(const bf16x8*)(pB0 + ko);
      if constexpr (BN == 128) rb1 = *(const bf16x8*)(pB1 + ko);
    }
    bf16x8 af[MF], bfr[4];
#pragma unroll
    for (int m = 0; m < MF; m++)
      af[m] = *(const bf16x8*)&As[cur][(wr * ROWS_W + m * 16 + l15) * 40 + l4 * 8];
#pragma unroll
    for (int n = 0; n < 4; n++)
      bfr[n] = *(const bf16x8*)&Bs[cur][(wc * 64 + n * 16 + l15) * 40 + l4 * 8];
#pragma unroll
    for (int m = 0; m < MF; m++)
#pragma unroll
      for (int n = 0; n < 4; n++)
        acc[m][n] = __builtin_amdgcn_mfma_f32_16x16x32_bf16(af[m], bfr[n], acc[m][n], 0, 0, 0);
  }
  if constexpr (BN == 128) {
    if (act == 2) {
      float csq_l[4];
#pragma unroll
      for (int n = 0; n < 4; n++) csq_l[n] = csqf[col0 + wc * 64 + n * 16 + l15];
      int cbase = col0 + wc * 64 + l15;
      int slot = ((col0 >> 7) << 1) + wc;
#pragma unroll
      for (int m = 0; m < 4; m++) {
#pragma unroll
        for (int r = 0; r < 4; r++) {
          float d0 = csq_l[0] - 2.f * acc[m][0][r];
          float d1 = csq_l[1] - 2.f * acc[m][1][r];
          float d2 = csq_l[2] - 2.f * acc[m][2][r];
          float d3 = csq_l[3] - 2.f * acc[m][3][r];
          int x0 = cbase, x1 = cbase + 16, x2 = cbase + 32, x3 = cbase + 48;
          cswap(d0, x0, d1, x1); cswap(d2, x2, d3, x3);
          cswap(d0, x0, d2, x2); cswap(d1, x1, d3, x3);
          cswap(d1, x1, d2, x2);
          for (int off = 1; off < 16; off <<= 1) {
            float e0 = __shfl_xor(d0, off), e1 = __shfl_xor(d1, off);
            float e2 = __shfl_xor(d2, off), e3 = __shfl_xor(d3, off);
            int y0 = __shfl_xor(x0, off), y1 = __shfl_xor(x1, off);
            int y2 = __shfl_xor(x2, off), y3 = __shfl_xor(x3, off);
            kmin(d0, x0, e3, y3); kmin(d1, x1, e2, y2);
            kmin(d2, x2, e1, y1); kmin(d3, x3, e0, y0);
            cswap(d0, x0, d2, x2); cswap(d1, x1, d3, x3);
            cswap(d0, x0, d1, x1); cswap(d2, x2, d3, x3);
          }
          if (l15 == 0) {
            int row = row0 + wr * 64 + m * 16 + l4 * 4 + r;
            float4 v1, v2;
            v1.x = d0; v1.y = d1;
            v1.z = __int_as_float(x0); v1.w = __int_as_float(x1);
            v2.x = d2; v2.y = d3;
            v2.z = __int_as_float(x2); v2.w = __int_as_float(x3);
            cand_part[(size_t)row * 32 + slot * 2]     = v1;
            cand_part[(size_t)row * 32 + slot * 2 + 1] = v2;
          }
        }
      }
      return;
    }
  }
#pragma unroll
  for (int m = 0; m < MF; m++) {
#pragma unroll
    for (int n = 0; n < 4; n++) {
      int col = col0 + wc * 64 + n * 16 + l15;
      float bv = bias ? bias[col] : 0.f;
#pragma unroll
      for (int r = 0; r < 4; r++) {
        int row = row0 + wr * ROWS_W + m * 16 + l4 * 4 + r;
        float v = acc[m][n][r] + bv;
        if (act == 1) v = gelu_f(v);
        if (resid) v += resid[(size_t)row * N + col];
        if (Cf) Cf[(size_t)row * N + col] = v;
        if (Cb) Cb[(size_t)row * N + col] = f2b(v);
      }
    }
  }
}

// ---------------- V transpose: src rows -> Vt [b*8+h][64][n_rows] ----------------
__global__ __launch_bounds__(256) void vt_kernel(
    const u16* __restrict__ src, size_t b_stride, int row_stride, int col0,
    int n_rows, u16* __restrict__ dst)
{
  __shared__ __attribute__((aligned(16))) u16 tile[32][72];
  int t = threadIdx.x;
  int bh = blockIdx.y;
  int b = bh >> 3, h = bh & 7;
  int n0 = blockIdx.x * 32;
  int n = t >> 3, dc = t & 7;
  *(bf16x8*)&tile[n][dc * 8] =
      *(const bf16x8*)(src + (size_t)b * b_stride + (size_t)(n0 + n) * row_stride + col0 + h * 64 + dc * 8);
  __syncthreads();
  int d = t >> 2, ns = t & 3;
  bf16x8 o;
#pragma unroll
  for (int i = 0; i < 8; i++) o[i] = (short)tile[ns * 8 + i][d];
  *(bf16x8*)(dst + ((size_t)bh * 64 + d) * n_rows + n0 + ns * 8) = o;
}

// ---------------- MFMA flash attention: 32 q/wave, split-K 4, cvt_pk (R17-exact) ----
__global__ __launch_bounds__(256, 4) void attn_mfma_kernel(
    const u16* __restrict__ Q, size_t q_bs, int q_stride,
    const u16* __restrict__ Kp, size_t k_bs, int k_stride, int k_extra,
    const u16* __restrict__ Vt, const int* __restrict__ mask,
    float scale, u16* __restrict__ Opart, float* __restrict__ MLpart,
    int n_keys)
{
  __shared__ __attribute__((aligned(16))) u16 Ks[8 * 64 * 8];
  __shared__ __attribute__((aligned(16))) u16 Vs[8 * 64 * 8];
  __shared__ __attribute__((aligned(16))) u16 Ps[4][8 * 32 * 8];
  __shared__ float mbias[64];
  int tid = threadIdx.x, lane = tid & 63, wave = tid >> 6;
  int flat = blockIdx.x + (blockIdx.y << 3) + (blockIdx.z << 6);
  int swz = ((flat & 7) << 7) + (flat >> 3);
  int qb = swz & 7, h = (swz >> 3) & 7, z = swz >> 6;
  int b = z & 3, split = z >> 2;
  int q0 = qb * 128 + wave * 32;
  int l15 = lane & 15, l4 = lane >> 4;
  int nq = n_keys >> 2;
  int nstart = split * nq, nend = nstart + nq;

  const u16* qrow = Q + (size_t)b * q_bs + (size_t)(q0 + l15) * q_stride + h * 64 + l4 * 8;
  bf16x8 qfA0 = *(const bf16x8*)qrow;
  bf16x8 qfA1 = *(const bf16x8*)(qrow + 32);
  const u16* qrowB = qrow + 16 * q_stride;
  bf16x8 qfB0 = *(const bf16x8*)qrowB;
  bf16x8 qfB1 = *(const bf16x8*)(qrowB + 32);
  f32x4 oA[4] = {}, oB[4] = {};
  float mA = -3.0e38f, lA = 0.f, mB = -3.0e38f, lB = 0.f;
  int srow = tid >> 2, schunk = tid & 3;
  const u16* kbase = Kp + (size_t)b * k_bs + k_extra + h * 64;
  const u16* vtbase = Vt + (size_t)(b * 8 + h) * 64 * n_keys;

  bf16x8 pk0, pk1, pv0, pv1;
  int pmv = 1;
  {
    const u16* krow = kbase + (size_t)(nstart + srow) * k_stride;
    pk0 = *(const bf16x8*)(krow + schunk * 8);
    pk1 = *(const bf16x8*)(krow + (schunk + 4) * 8);
    const u16* vrow = vtbase + (size_t)srow * n_keys + nstart;
    pv0 = *(const bf16x8*)(vrow + schunk * 8);
    pv1 = *(const bf16x8*)(vrow + (schunk + 4) * 8);
    if (mask && tid < 64) pmv = mask[(size_t)b * n_keys + nstart + tid];
  }

  for (int n0 = nstart; n0 < nend; n0 += 64) {
    __syncthreads();
    *(bf16x8*)&Ks[(schunk * 64 + srow) * 8]       = pk0;
    *(bf16x8*)&Ks[((schunk + 4) * 64 + srow) * 8] = pk1;
    *(bf16x8*)&Vs[(schunk * 64 + srow) * 8]       = pv0;
    *(bf16x8*)&Vs[((schunk + 4) * 64 + srow) * 8] = pv1;
    if (tid < 64) mbias[tid] = (mask && !pmv) ? -3.0e38f : 0.f;
    __syncthreads();
    if (n0 + 64 < nend) {
      const u16* krow = kbase + (size_t)(n0 + 64 + srow) * k_stride;
      pk0 = *(const bf16x8*)(krow + schunk * 8);
      pk1 = *(const bf16x8*)(krow + (schunk + 4) * 8);
      const u16* vrow = vtbase + (size_t)srow * n_keys + n0 + 64;
      pv0 = *(const bf16x8*)(vrow + schunk * 8);
      pv1 = *(const bf16x8*)(vrow + (schunk + 4) * 8);
      if (mask && tid < 64) pmv = mask[(size_t)b * n_keys + n0 + 64 + tid];
    }
    f32x4 sacA[4], sacB[4];
#pragma unroll
    for (int kb = 0; kb < 4; kb++) {
      bf16x8 kf0 = *(const bf16x8*)&Ks[(l4 * 64 + kb * 16 + l15) * 8];
      bf16x8 kf1 = *(const bf16x8*)&Ks[((l4 + 4) * 64 + kb * 16 + l15) * 8];
      f32x4 za = {}, zb = {};
      za = __builtin_amdgcn_mfma_f32_16x16x32_bf16(kf0, qfA0, za, 0, 0, 0);
      sacA[kb] = __builtin_amdgcn_mfma_f32_16x16x32_bf16(kf1, qfA1, za, 0, 0, 0);
      zb = __builtin_amdgcn_mfma_f32_16x16x32_bf16(kf0, qfB0, zb, 0, 0, 0);
      sacB[kb] = __builtin_amdgcn_mfma_f32_16x16x32_bf16(kf1, qfB1, zb, 0, 0, 0);
    }
    // ---- softmax half A (query = l15) ----
    {
      float pmax = -3.0e38f;
#pragma unroll
      for (int kb = 0; kb < 4; kb++) {
        float4 bs = *(const float4*)&mbias[kb * 16 + l4 * 4];
        sacA[kb][0] = fmaf(sacA[kb][0], scale, bs.x);
        sacA[kb][1] = fmaf(sacA[kb][1], scale, bs.y);
        sacA[kb][2] = fmaf(sacA[kb][2], scale, bs.z);
        sacA[kb][3] = fmaf(sacA[kb][3], scale, bs.w);
#pragma unroll
        for (int r = 0; r < 4; r++) pmax = fmaxf(pmax, sacA[kb][r]);
      }
      pmax = fmaxf(pmax, __shfl_xor(pmax, 16));
      pmax = fmaxf(pmax, __shfl_xor(pmax, 32));
      if (!__all(pmax - mA <= 11.5f)) {
        float mnew = fmaxf(mA, pmax);
        float al = ex2(mA - mnew);
        lA *= al;
        mA = mnew;
        float alr[4];
#pragma unroll
        for (int r = 0; r < 4; r++) alr[r] = __shfl(al, l4 * 4 + r, 64);
#pragma unroll
        for (int nb = 0; nb < 4; nb++)
#pragma unroll
          for (int r = 0; r < 4; r++) oA[nb][r] *= alr[r];
      }
      float psum = 0.f;
#pragma unroll
      for (int kb = 0; kb < 4; kb++) {
        float p0 = ex2(sacA[kb][0] - mA);
        float p1 = ex2(sacA[kb][1] - mA);
        float p2 = ex2(sacA[kb][2] - mA);
        float p3 = ex2(sacA[kb][3] - mA);
        psum += (p0 + p1) + (p2 + p3);
        uint2 w;
        w.x = cvtpk(p0, p1);
        w.y = cvtpk(p2, p3);
        *(uint2*)&Ps[wave][((kb * 2 + (l4 >> 1)) * 32 + l15) * 8 + (l4 & 1) * 4] = w;
      }
      psum += __shfl_xor(psum, 16);
      psum += __shfl_xor(psum, 32);
      lA += psum;
    }
    // ---- softmax half B (query = 16 + l15) ----
    {
      float pmax = -3.0e38f;
#pragma unroll
      for (int kb = 0; kb < 4; kb++) {
        float4 bs = *(const float4*)&mbias[kb * 16 + l4 * 4];
        sacB[kb][0] = fmaf(sacB[kb][0], scale, bs.x);
        sacB[kb][1] = fmaf(sacB[kb][1], scale, bs.y);
        sacB[kb][2] = fmaf(sacB[kb][2], scale, bs.z);
        sacB[kb][3] = fmaf(sacB[kb][3], scale, bs.w);
#pragma unroll
        for (int r = 0; r < 4; r++) pmax = fmaxf(pmax, sacB[kb][r]);
      }
      pmax = fmaxf(pmax, __shfl_xor(pmax, 16));
      pmax = fmaxf(pmax, __shfl_xor(pmax, 32));
      if (!__all(pmax - mB <= 11.5f)) {
        float mnew = fmaxf(mB, pmax);
        float al = ex2(mB - mnew);
        lB *= al;
        mB = mnew;
        float alr[4];
#pragma unroll
        for (int r = 0; r < 4; r++) alr[r] = __shfl(al, l4 * 4 + r, 64);
#pragma unroll
        for (int nb = 0; nb < 4; nb++)
#pragma unroll
          for (int r = 0; r < 4; r++) oB[nb][r] *= alr[r];
      }
      float psum = 0.f;
#pragma unroll
      for (int kb = 0; kb < 4; kb++) {
        float p0 = ex2(sacB[kb][0] - mB);
        float p1 = ex2(sacB[kb][1] - mB);
        float p2 = ex2(sacB[kb][2] - mB);
        float p3 = ex2(sacB[kb][3] - mB);
        psum += (p0 + p1) + (p2 + p3);
        uint2 w;
        w.x = cvtpk(p0, p1);
        w.y = cvtpk(p2, p3);
        *(uint2*)&Ps[wave][((kb * 2 + (l4 >> 1)) * 32 + 16 + l15) * 8 + (l4 & 1) * 4] = w;
      }
      psum += __shfl_xor(psum, 16);
      psum += __shfl_xor(psum, 32);
      lB += psum;
    }
    // ---- PV: V-frags read once, shared by both halves ----
#pragma unroll
    for (int c = 0; c < 2; c++) {
      bf16x8 pfA = *(const bf16x8*)&Ps[wave][((c * 4 + l4) * 32 + l15) * 8];
      bf16x8 pfB = *(const bf16x8*)&Ps[wave][((c * 4 + l4) * 32 + 16 + l15) * 8];
#pragma unroll
      for (int nb = 0; nb < 4; nb++) {
        bf16x8 vf = *(const bf16x8*)&Vs[((c * 4 + l4) * 64 + nb * 16 + l15) * 8];
        oA[nb] = __builtin_amdgcn_mfma_f32_16x16x32_bf16(pfA, vf, oA[nb], 0, 0, 0);
        oB[nb] = __builtin_amdgcn_mfma_f32_16x16x32_bf16(pfB, vf, oB[nb], 0, 0, 0);
      }
    }
  }
  int pr_base = ((split * 4 + b) * 8 + h) * 1024;
#pragma unroll
  for (int nb = 0; nb < 4; nb++)
#pragma unroll
    for (int r = 0; r < 4; r++) {
      Opart[(size_t)(pr_base + q0 + l4 * 4 + r) * 64 + nb * 16 + l15] = f2b(oA[nb][r]);
      Opart[(size_t)(pr_base + q0 + 16 + l4 * 4 + r) * 64 + nb * 16 + l15] = f2b(oB[nb][r]);
    }
  if (lane < 16) {
    int pr = pr_base + q0 + lane;
    MLpart[2 * pr]     = mA;
    MLpart[2 * pr + 1] = lA;
  } else if (lane < 32) {
    int pr = pr_base + q0 + 16 + l15;
    MLpart[2 * pr]     = mB;
    MLpart[2 * pr + 1] = lB;
  }
}

// ---------------- combine the 4 split-K partials (base-2 weights) ----------------
__global__ __launch_bounds__(256) void attn_combine_kernel(
    const u16* __restrict__ Opart, const float* __restrict__ MLpart,
    u16* __restrict__ O, size_t o_bs)
{
  int idx = blockIdx.x * 256 + threadIdx.x;
  int d = idx & 63, gq = idx >> 6;
  int row = gq & 1023, bh = gq >> 10;
  int h = bh & 7, b = bh >> 3;
  float m[4], l[4];
  int pr[4];
#pragma unroll
  for (int s = 0; s < 4; s++) {
    pr[s] = ((s * 4 + b) * 8 + h) * 1024 + row;
    m[s] = MLpart[2 * pr[s]];
    l[s] = MLpart[2 * pr[s] + 1];
  }
  float mmax = fmaxf(fmaxf(m[0], m[1]), fmaxf(m[2], m[3]));
  float lsum = 0.f, osum = 0.f;
#pragma unroll
  for (int s = 0; s < 4; s++) {
    float w = ex2(m[s] - mmax);
    lsum += l[s] * w;
    osum += b2f(Opart[(size_t)pr[s] * 64 + d]) * w;
  }
  O[(size_t)b * o_bs + (size_t)row * 512 + h * 64 + d] = f2b(osum / lsum);
}

// ---------------- fused gather + scalars ----------------
__global__ __launch_bounds__(128) void gather_scalars_kernel(
    const float* __restrict__ x2, const int* __restrict__ idx,
    const float* __restrict__ counts, const double* __restrict__ commit_partial,
    float* __restrict__ out, float* __restrict__ out_tail)
{
  int t = blockIdx.x;
  int tid = threadIdx.x;
  if (t < 8192) {
    int b = t >> 11;
    int code = idx[t];
    const float4* src = (const float4*)(x2 + ((size_t)(b * M_ + code) << 9));
    float4* dst = (float4*)(out + ((size_t)t << 9));
    dst[tid] = src[tid];
    return;
  }
  double cs = 0.0;
#pragma unroll
  for (int i = 0; i < 64; i++) cs += commit_partial[tid + i * 128];
  double e = 0.0;
#pragma unroll
  for (int i = 0; i < 8; i++) {
    double p = (double)counts[tid + i * 128] / 8192.0;
    e += p * log(p + 1e-10);
  }
  for (int off = 32; off; off >>= 1) {
    cs += __shfl_down(cs, off);
    e  += __shfl_down(e, off);
  }
  __shared__ double redc[2], rede[2];
  if ((tid & 63) == 0) { redc[tid >> 6] = cs; rede[tid >> 6] = e; }
  __syncthreads();
  if (tid == 0) {
    out_tail[0] = (float)((redc[0] + redc[1]) / (8192.0 * 512.0));
    out_tail[1] = (float)exp(-(rede[0] + rede[1]));
  }
}

extern "C" void kernel_launch(void* const* d_in, const int* in_sizes, int n_in,
                              void* d_out, int out_size, void* d_ws, size_t ws_size,
                              hipStream_t stream) {
  const float* ctx      = (const float*)d_in[0];
  const void*  mask_raw = d_in[1];
  const float* codebook = (const float*)d_in[2];
  const float* norm_g   = (const float*)d_in[3];
  const float* norm_b   = (const float*)d_in[4];
  const float* cnorm_g  = (const float*)d_in[5];
  const float* cnorm_b  = (const float*)d_in[6];
  const float* wq       = (const float*)d_in[7];
  const float* wkv      = (const float*)d_in[8];
  const float* wo       = (const float*)d_in[9];
  const float* wo_b     = (const float*)d_in[10];
  const float* a_norm_g = (const float*)d_in[11];
  const float* a_norm_b = (const float*)d_in[12];
  const float* a_qkv    = (const float*)d_in[13];
  const float* a_out    = (const float*)d_in[14];
  const float* f_norm_g = (const float*)d_in[15];
  const float* f_norm_b = (const float*)d_in[16];
  const float* f_w1     = (const float*)d_in[17];
  const float* f_w2     = (const float*)d_in[18];
  float* out = (float*)d_out;
  const float LOG2E = 1.4426950408889634f;

  char* ws = (char*)d_ws;
  float*  counts     = (float*)(ws + 128);
  double* code_sq    = (double*)(ws + 4224);
  float*  csqf       = (float*)(ws + 12416);
  int*    indices    = (int*)(ws + 16512);
  int*    mask_norm  = (int*)(ws + 49280);
  double* commit_partial = (double*)(ws + 262144);

  char* pool = ws + (1 << 20);
  u16*   vqA  = (u16*)(pool);
  u16*   vqBT = (u16*)(pool + ((size_t)25 << 20));
  float4* cand_part = (float4*)(pool + ((size_t)30 << 20));
  float* attn_ml = (float*)(pool + ((size_t)61 << 20));  // free region: 61-62MB
  char* regA  = pool;
  char* regB  = pool + ((size_t)16 << 20);
  char* regC  = pool + ((size_t)24 << 20);
  char* regD  = pool + ((size_t)32 << 20);
  char* regE  = pool + ((size_t)40 << 20);
  char* regF  = pool + ((size_t)44 << 20);
  size_t woff = (1 << 20) + ((size_t)64 << 20);
  u16* wqT    = (u16*)(ws + woff); woff += (size_t)512 * 512 * 2;
  u16* wkvT   = (u16*)(ws + woff); woff += (size_t)1024 * 512 * 2;
  u16* woT    = (u16*)(ws + woff); woff += (size_t)512 * 512 * 2;
  u16* aqkvT  = (u16*)(ws + woff); woff += (size_t)1536 * 512 * 2;
  u16* aoutT  = (u16*)(ws + woff); woff += (size_t)512 * 512 * 2;
  u16* fw1T   = (u16*)(ws + woff); woff += (size_t)1024 * 512 * 2;
  u16* fw2T   = (u16*)(ws + woff); woff += (size_t)512 * 1024 * 2;
  u16* xq_b   = (u16*)(ws + woff); woff += (size_t)1024 * 512 * 2;
  u16* qs_b   = (u16*)(ws + woff); woff += (size_t)1024 * 512 * 2;

  u16* kv_b     = (u16*)regA;
  u16* qkv2_b   = (u16*)regA;
  u16* ctx_ln_b = (u16*)regB;
  u16* VtS      = (u16*)regB;
  u16* VtX      = (u16*)regC;
  float* x1_f   = (float*)regC;
  float* x0_f   = (float*)regD;
  u16* att_out_b = (u16*)regE;
  u16* h_b       = (u16*)regE;
  u16* o2_b      = (u16*)regE;
  u16* hf_b      = (u16*)regE;
  u16* g_b      = (u16*)regF;
  float* x2_f   = (float*)(pool + ((size_t)52 << 20));
  u16* attn_part = (u16*)regF;

  // ---- mega prep (1 launch): detect+masknorm, convs, code_sq, input LNs, wconv ----
  WJobs jobs;
  jobs.src[0] = wq;    jobs.dst[0] = wqT;   jobs.K[0] = 512;  jobs.N[0] = 512;
  jobs.src[1] = wkv;   jobs.dst[1] = wkvT;  jobs.K[1] = 512;  jobs.N[1] = 1024;
  jobs.src[2] = wo;    jobs.dst[2] = woT;   jobs.K[2] = 512;  jobs.N[2] = 512;
  jobs.src[3] = a_qkv; jobs.dst[3] = aqkvT; jobs.K[3] = 512;  jobs.N[3] = 1536;
  jobs.src[4] = a_out; jobs.dst[4] = aoutT; jobs.K[4] = 512;  jobs.N[4] = 512;
  jobs.src[5] = f_w1;  jobs.dst[5] = fw1T;  jobs.K[5] = 512;  jobs.N[5] = 1024;
  jobs.src[6] = f_w2;  jobs.dst[6] = fw2T;  jobs.K[6] = 1024; jobs.N[6] = 512;
  int acc_b = 0;
  for (int i = 0; i < 7; i++) {
    jobs.b0[i] = acc_b;
    acc_b += (jobs.K[i] >> 5) * (jobs.N[i] >> 5);
  }
  jobs.b0[7] = acc_b;
  prep_kernel<<<12545 + acc_b, 256, 0, stream>>>(
      mask_raw, mask_norm, ctx, vqA, codebook, vqBT,
      norm_g, norm_b, xq_b, cnorm_g, cnorm_b, ctx_ln_b,
      code_sq, csqf, counts, jobs);

  // ---- VQ distance GEMM + fused top4/refine ----
  gemm_bf16_kernel<128><<<dim3(8, 64), 256, 0, stream>>>(vqA, vqBT, nullptr, nullptr,
                                                    nullptr, nullptr, csqf, cand_part,
                                                    8192, 1024, 512, 2);
  vq_refine4_kernel<<<2048, 256, 0, stream>>>(ctx, codebook, code_sq, cand_part, indices,
                                              commit_partial, counts);

  // ---- Cross-attention ----
  gemm_bf16_kernel<64><<<dim3(8, 8), 256, 0, stream>>>(xq_b, wqT, nullptr, nullptr,
                                                   nullptr, qs_b, nullptr, nullptr,
                                                   1024, 512, 512, 0);
  gemm_bf16_kernel<128><<<dim3(8, 64), 256, 0, stream>>>(ctx_ln_b, wkvT, nullptr, nullptr,
                                                    nullptr, kv_b, nullptr, nullptr,
                                                    8192, 1024, 512, 0);
  vt_kernel<<<dim3(64, 32), 256, 0, stream>>>(kv_b, (size_t)2048 * 1024, 1024, 512, 2048, VtX);
  attn_mfma_kernel<<<dim3(8, 8, 16), 256, 0, stream>>>(
      qs_b, 0, 512, kv_b, (size_t)2048 * 1024, 1024, 0, VtX, mask_norm,
      0.125f * LOG2E, attn_part, attn_ml, 2048);
  attn_combine_kernel<<<8192, 256, 0, stream>>>(attn_part, attn_ml, att_out_b, (size_t)1024 * 512);
  gemm_bf16_kernel<64><<<dim3(8, 32), 256, 0, stream>>>(att_out_b, woT, wo_b, nullptr,
                                                    x0_f, nullptr, nullptr, nullptr,
                                                    4096, 512, 512, 0);

  // ---- Transformer refinement ----
  ln_rows_kernel<<<4096, 256, 0, stream>>>(x0_f, a_norm_g, a_norm_b, h_b);
  gemm_bf16_kernel<64><<<dim3(24, 32), 256, 0, stream>>>(h_b, aqkvT, nullptr, nullptr,
                                                     nullptr, qkv2_b, nullptr, nullptr,
                                                     4096, 1536, 512, 0);
  vt_kernel<<<dim3(32, 32), 256, 0, stream>>>(qkv2_b, (size_t)1024 * 1536, 1536, 1024, 1024, VtS);
  attn_mfma_kernel<<<dim3(8, 8, 16), 256, 0, stream>>>(
      qkv2_b, (size_t)1024 * 1536, 1536, qkv2_b, (size_t)1024 * 1536, 1536, 512, VtS, nullptr,
      0.125f * LOG2E, attn_part, attn_ml, 1024);
  attn_combine_kernel<<<8192, 256, 0, stream>>>(attn_part, attn_ml, o2_b, (size_t)1024 * 512);
  gemm_bf16_kernel<64><<<dim3(8, 32), 256, 0, stream>>>(o2_b, aoutT, nullptr, x0_f,
                                                    x1_f, nullptr, nullptr, nullptr,
                                                    4096, 512, 512, 0);
  ln_rows_kernel<<<4096, 256, 0, stream>>>(x1_f, f_norm_g, f_norm_b, hf_b);
  gemm_bf16_kernel<64><<<dim3(16, 32), 256, 0, stream>>>(hf_b, fw1T, nullptr, nullptr,
                                                    nullptr, g_b, nullptr, nullptr,
                                                    4096, 1024, 512, 1);
  gemm_bf16_kernel<64><<<dim3(8, 32), 256, 0, stream>>>(g_b, fw2T, nullptr, x1_f,
                                                    x2_f, nullptr, nullptr, nullptr,
                                                    4096, 512, 1024, 0);

  // ---- fused gather + scalars ----
  gather_scalars_kernel<<<8193, 128, 0, stream>>>(x2_f, indices, counts, commit_partial,
                                                  out, out + (size_t)B_ * N_ * D_);
}